// Round 13
// baseline (180.280 us; speedup 1.0000x reference)
//
#include <hip/hip_runtime.h>
#include <stdint.h>
#include <math.h>

#define B_ 2
#define S_ 2048
#define D_ 1024
#define H_ 16
#define HD_ 64
#define KVBLK 64

typedef __bf16 bf16_t;
typedef __bf16 bf16x4 __attribute__((ext_vector_type(4)));
typedef __bf16 bf16x8 __attribute__((ext_vector_type(8)));
typedef float f32x4 __attribute__((ext_vector_type(4)));
typedef float f32x16 __attribute__((ext_vector_type(16)));
typedef float float4v __attribute__((ext_vector_type(4)));

#define L2E 1.4426950408889634f
#define NINF (-__builtin_inff())

__device__ __forceinline__ void gload_lds16(const bf16_t* g, bf16_t* l) {
  __builtin_amdgcn_global_load_lds((const __attribute__((address_space(1))) void*)g,
                                   (__attribute__((address_space(3))) void*)l, 16, 0, 0);
}

__device__ __forceinline__ uint32_t packbf(float a, float b) {
  union { __bf16 h[2]; uint32_t u; } cvt;
  cvt.h[0] = (__bf16)a; cvt.h[1] = (__bf16)b;
  return cvt.u;
}

// ---------------- fused cast f32 -> bf16 for all three inputs (vector x4) ----------------
__global__ void cast3_bf16_kernel(const float* __restrict__ s0, bf16_t* __restrict__ d0, int n0,
                                  const float* __restrict__ s1, bf16_t* __restrict__ d1, int n1,
                                  const float* __restrict__ s2, bf16_t* __restrict__ d2, int n2) {
  int i = blockIdx.x * blockDim.x + threadIdx.x;
  int stride = gridDim.x * blockDim.x;
  int tot = n0 + n1 + n2;
  for (; i < tot; i += stride) {
    const float* s; bf16_t* d; int j = i;
    if (j < n0) { s = s0; d = d0; }
    else if ((j -= n0) < n1) { s = s1; d = d1; }
    else { j -= n1; s = s2; d = d2; }
    float4v f = *(const float4v*)(s + (size_t)j * 4);
    bf16x4 o;
    o[0] = (__bf16)f[0]; o[1] = (__bf16)f[1]; o[2] = (__bf16)f[2]; o[3] = (__bf16)f[3];
    *(bf16x4*)(d + (size_t)j * 4) = o;
  }
}

// ---------------- small GEMM (128^2, m97 structure) for gemm2 (fp32 out: 64B row segs, OK) ----------------
template <typename OutT>
__global__ __launch_bounds__(256) void gemm_bt(const bf16_t* __restrict__ A,
                                               const bf16_t* __restrict__ Bm,
                                               OutT* __restrict__ C,
                                               int M, int N, int K) {
  __shared__ bf16_t As[128 * 32];
  __shared__ bf16_t Bs[128 * 32];
  const int t = threadIdx.x;
  const int lane = t & 63, wave = t >> 6;
  const int wr = wave >> 1, wc = wave & 1;
  const int qr = lane & 15, g = lane >> 4;
  const int bm = blockIdx.x, bn = blockIdx.y;

  f32x4 acc[4][4];
#pragma unroll
  for (int m = 0; m < 4; m++)
#pragma unroll
    for (int n = 0; n < 4; n++) acc[m][n] = (f32x4){0.f, 0.f, 0.f, 0.f};

  const bf16_t* Abase = A + (size_t)(bm * 128) * K;
  const bf16_t* Bbase = Bm + (size_t)(bn * 128) * K;
  const int srow = t >> 2;
  const int scol = (t & 3) * 8;

  for (int kk = 0; kk < K; kk += 32) {
    gload_lds16(Abase + (size_t)srow * K + kk + scol,        As + t * 8);
    gload_lds16(Abase + (size_t)(srow + 64) * K + kk + scol, As + 2048 + t * 8);
    gload_lds16(Bbase + (size_t)srow * K + kk + scol,        Bs + t * 8);
    gload_lds16(Bbase + (size_t)(srow + 64) * K + kk + scol, Bs + 2048 + t * 8);
    __syncthreads();
    bf16x8 a[4], b[4];
#pragma unroll
    for (int m = 0; m < 4; m++)
      a[m] = *(const bf16x8*)(As + (wr * 64 + m * 16 + qr) * 32 + g * 8);
#pragma unroll
    for (int n = 0; n < 4; n++)
      b[n] = *(const bf16x8*)(Bs + (wc * 64 + n * 16 + qr) * 32 + g * 8);
#pragma unroll
    for (int m = 0; m < 4; m++)
#pragma unroll
      for (int n = 0; n < 4; n++)
        acc[m][n] = __builtin_amdgcn_mfma_f32_16x16x32_bf16(a[m], b[n], acc[m][n], 0, 0, 0);
    __syncthreads();
  }

#pragma unroll
  for (int m = 0; m < 4; m++) {
    int row0 = bm * 128 + wr * 64 + m * 16 + g * 4;
#pragma unroll
    for (int n = 0; n < 4; n++) {
      int col = bn * 128 + wc * 64 + n * 16 + qr;
#pragma unroll
      for (int r = 0; r < 4; r++)
        C[(size_t)(row0 + r) * N + col] = (OutT)acc[m][n][r];
    }
  }
}

// ---- fused QKV GEMM + RoPE + q-scale + V-transpose: 256^2, BK=64, 8-wave, phase-pipelined ----
// Core loop = R10/R11 race-proven gemm256. R12 lesson: the direct scatter epilogue caused 6.8x
// write amplification (WRITE_SIZE 170MB, write-bound 82us). Fix: stage each wave's 128x64
// output tile in LDS (As/Bs dead after the K-loop; waves 0-3 use As, 4-7 use Bs; 16KB/wave,
// 16B-chunk XOR swizzle) then write coalesced: Q/K 1KB-contiguous per instr, Vt 4x256B.
__global__ __launch_bounds__(512, 1) void gemm_qkv_rope(const bf16_t* __restrict__ A,
                                                        const bf16_t* __restrict__ Bm,
                                                        const int* __restrict__ pos,
                                                        bf16_t* __restrict__ Qd,
                                                        bf16_t* __restrict__ Kd,
                                                        bf16_t* __restrict__ Vtd) {
  const int K = D_;                 // 1024
  const int NT = K >> 6;
  __shared__ bf16_t As[2][256 * 64];
  __shared__ bf16_t Bs[2][256 * 64];
  const int t = threadIdx.x;
  const int lane = t & 63, wid = t >> 6;
  const int qr = lane & 15, g = lane >> 4;
  const int wm = wid >> 2, wn = wid & 3;
  const int bm = blockIdx.x, bn = blockIdx.y;

  const bf16_t* Ab = A + (size_t)(bm * 256) * K;
  const bf16_t* Bb = Bm + (size_t)(bn * 256) * K;

  const bf16_t* srcA[4];
  const bf16_t* srcB[4];
  int ldsOff[4];
#pragma unroll
  for (int i = 0; i < 4; i++) {
    int e = t + 512 * i;
    int row = e >> 3, cs = e & 7;
    int gcol = (cs ^ (row & 7)) * 8;
    srcA[i] = Ab + (size_t)row * K + gcol;
    srcB[i] = Bb + (size_t)row * K + gcol;
    ldsOff[i] = e * 8;
  }

  f32x4 acc[8][4];
#pragma unroll
  for (int m = 0; m < 8; m++)
#pragma unroll
    for (int n = 0; n < 4; n++) acc[m][n] = (f32x4){0.f, 0.f, 0.f, 0.f};

#define RD(buf_, r_, k_) (*(const bf16x8*)((buf_) + (r_) * 64 + ((((k_) * 4 + g) ^ ((r_) & 7)) * 8)))

#pragma unroll
  for (int i = 0; i < 4; i++) gload_lds16(srcA[i], As[0] + ldsOff[i]);
#pragma unroll
  for (int i = 0; i < 4; i++) gload_lds16(srcB[i], Bs[0] + ldsOff[i]);
#pragma unroll
  for (int i = 0; i < 4; i++) gload_lds16(srcA[i] + 64, As[1] + ldsOff[i]);
#pragma unroll
  for (int i = 0; i < 4; i++) gload_lds16(srcB[i] + 64, Bs[1] + ldsOff[i]);

  for (int T = 0; T < NT; ++T) {
    bf16_t* A_c = As[T & 1];
    bf16_t* B_c = Bs[T & 1];
    if (T + 1 < NT) asm volatile("s_waitcnt vmcnt(8)" ::: "memory");
    else            asm volatile("s_waitcnt vmcnt(0)" ::: "memory");
    __builtin_amdgcn_sched_barrier(0);
    __builtin_amdgcn_s_barrier();

    const bool st = (T + 2 < NT);
    const int kt2 = (T + 2) * 64;

    bf16x8 alo[4][2], ahi[4][2], bfr[4][2];

    // ---- ph0: read a_lo (regions 0,2) + b01; MFMA m0-3 x n0-1 ----
#pragma unroll
    for (int m = 0; m < 4; m++) {
      int r = wm * 128 + m * 16 + qr;
      alo[m][0] = RD(A_c, r, 0); alo[m][1] = RD(A_c, r, 1);
    }
#pragma unroll
    for (int n = 0; n < 2; n++) {
      int r = wn * 64 + n * 16 + qr;
      bfr[n][0] = RD(B_c, r, 0); bfr[n][1] = RD(B_c, r, 1);
    }
    __builtin_amdgcn_s_barrier();
    __builtin_amdgcn_s_setprio(1);
#pragma unroll
    for (int m = 0; m < 4; m++)
#pragma unroll
      for (int n = 0; n < 2; n++)
#pragma unroll
        for (int k = 0; k < 2; k++)
          acc[m][n] = __builtin_amdgcn_mfma_f32_16x16x32_bf16(alo[m][k], bfr[n][k], acc[m][n], 0, 0, 0);
    __builtin_amdgcn_s_setprio(0);
    __builtin_amdgcn_s_barrier();

    // ---- ph1: read b23; stage T+2 A regions {0,2}; MFMA m0-3 x n2-3 ----
#pragma unroll
    for (int n = 2; n < 4; n++) {
      int r = wn * 64 + n * 16 + qr;
      bfr[n][0] = RD(B_c, r, 0); bfr[n][1] = RD(B_c, r, 1);
    }
    if (st) {
      gload_lds16(srcA[0] + kt2, A_c + ldsOff[0]);
      gload_lds16(srcA[2] + kt2, A_c + ldsOff[2]);
    }
    __builtin_amdgcn_s_barrier();
    __builtin_amdgcn_s_setprio(1);
#pragma unroll
    for (int m = 0; m < 4; m++)
#pragma unroll
      for (int n = 2; n < 4; n++)
#pragma unroll
        for (int k = 0; k < 2; k++)
          acc[m][n] = __builtin_amdgcn_mfma_f32_16x16x32_bf16(alo[m][k], bfr[n][k], acc[m][n], 0, 0, 0);
    __builtin_amdgcn_s_setprio(0);
    __builtin_amdgcn_s_barrier();

    // ---- ph2: read a_hi (regions 1,3); stage T+2 B; MFMA m4-7 x n0-1 ----
#pragma unroll
    for (int m = 0; m < 4; m++) {
      int r = wm * 128 + (m + 4) * 16 + qr;
      ahi[m][0] = RD(A_c, r, 0); ahi[m][1] = RD(A_c, r, 1);
    }
    if (st) {
      gload_lds16(srcB[0] + kt2, B_c + ldsOff[0]);
      gload_lds16(srcB[1] + kt2, B_c + ldsOff[1]);
      gload_lds16(srcB[2] + kt2, B_c + ldsOff[2]);
      gload_lds16(srcB[3] + kt2, B_c + ldsOff[3]);
    }
    __builtin_amdgcn_s_barrier();
    __builtin_amdgcn_s_setprio(1);
#pragma unroll
    for (int m = 0; m < 4; m++)
#pragma unroll
      for (int n = 0; n < 2; n++)
#pragma unroll
        for (int k = 0; k < 2; k++)
          acc[m + 4][n] = __builtin_amdgcn_mfma_f32_16x16x32_bf16(ahi[m][k], bfr[n][k], acc[m + 4][n], 0, 0, 0);
    __builtin_amdgcn_s_setprio(0);
    __builtin_amdgcn_s_barrier();

    // ---- ph3: stage T+2 A regions {1,3}; MFMA m4-7 x n2-3 ----
    if (st) {
      gload_lds16(srcA[1] + kt2, A_c + ldsOff[1]);
      gload_lds16(srcA[3] + kt2, A_c + ldsOff[3]);
    }
    __builtin_amdgcn_s_barrier();
    __builtin_amdgcn_s_setprio(1);
#pragma unroll
    for (int m = 0; m < 4; m++)
#pragma unroll
      for (int n = 2; n < 4; n++)
#pragma unroll
        for (int k = 0; k < 2; k++)
          acc[m + 4][n] = __builtin_amdgcn_mfma_f32_16x16x32_bf16(ahi[m][k], bfr[n][k], acc[m + 4][n], 0, 0, 0);
    __builtin_amdgcn_s_setprio(0);
    __builtin_amdgcn_s_barrier();
  }
#undef RD

  // ---- fused epilogue via per-wave LDS staging (coalesced stores) ----
  __syncthreads();  // all waves done with As/Bs (K-loop reads consumed)
  bf16_t* myLds = (wid < 4) ? ((bf16_t*)As + wid * 8192) : ((bf16_t*)Bs + (wid - 4) * 8192);

  const int w = bn * 4 + wn;        // window 0..47
  const int typ = w % 3;            // 0=q, 1=k, 2=v
  const int head = w / 3;
  const int rowbase = bm * 256 + wm * 128;       // multiple of 128 -> single batch
  const int b = rowbase >> 11;
  const int s0w = rowbase & (S_ - 1);

  if (typ == 2) {
    // stage [d][s_local] swizzled: addr = d*128 + ((sc ^ (d&15))*8) + (s&7)
#pragma unroll
    for (int m = 0; m < 8; m++) {
      int sl0 = m * 16 + g * 4;
#pragma unroll
      for (int n = 0; n < 4; n++) {
        int d = n * 16 + qr;
#pragma unroll
        for (int rr = 0; rr < 4; rr++) {
          int sl = sl0 + rr;
          myLds[d * 128 + (((sl >> 3) ^ (d & 15)) * 8) + (sl & 7)] = (__bf16)acc[m][n][rr];
        }
      }
    }
    bf16_t* dstv = Vtd + (size_t)(b * H_ + head) * HD_ * S_ + s0w;
#pragma unroll
    for (int it = 0; it < 16; it++) {
      int d = (lane >> 4) + it * 4;
      int sc = lane & 15;
      bf16x8 v = *(const bf16x8*)(myLds + d * 128 + ((sc ^ (d & 15)) * 8));
      *(bf16x8*)(dstv + (size_t)d * S_ + sc * 8) = v;
    }
  } else {
    // rope + stage [r][d] swizzled: addr = r*64 + ((d>>3 ^ (r&7))*8) + (d&7)
    const float qs = (typ == 0) ? 0.125f : 1.0f;
    const float l2r = 13.287712379549449f / 32.0f;
    float inv[2];
    inv[0] = exp2f(-(float)qr * l2r);
    inv[1] = exp2f(-(float)(qr + 16) * l2r);
#pragma unroll
    for (int m = 0; m < 8; m++) {
      int r0 = m * 16 + g * 4;
#pragma unroll
      for (int rr = 0; rr < 4; rr++) {
        int r = r0 + rr;
        float p = (float)pos[rowbase + r];
#pragma unroll
        for (int n = 0; n < 2; n++) {
          float ang = p * inv[n];
          float sn, cs;
          sincosf(ang, &sn, &cs);
          float x1 = acc[m][n][rr], x2 = acc[m][n + 2][rr];
          float o1 = (x1 * cs - x2 * sn) * qs;
          float o2 = (x2 * cs + x1 * sn) * qs;
          int d1 = n * 16 + qr, d2 = d1 + 32;
          myLds[r * 64 + (((d1 >> 3) ^ (r & 7)) * 8) + (d1 & 7)] = (__bf16)o1;
          myLds[r * 64 + (((d2 >> 3) ^ (r & 7)) * 8) + (d2 & 7)] = (__bf16)o2;
        }
      }
    }
    bf16_t* dstb = ((typ == 0) ? Qd : Kd) + (size_t)(b * H_ + head) * S_ * HD_ + (size_t)s0w * HD_;
#pragma unroll
    for (int it = 0; it < 16; it++) {
      int r = (lane >> 3) + it * 8;
      int cc = lane & 7;
      bf16x8 v = *(const bf16x8*)(myLds + r * 64 + ((cc ^ (r & 7)) * 8));
      *(bf16x8*)(dstb + (size_t)r * HD_ + cc * 8) = v;
    }
  }
}

// ---------------- flash attention: split-KV (2 halves) + XCD-resident KV mapping ----------------
__global__ __launch_bounds__(256) void attn_kernel(const bf16_t* __restrict__ Q,
                                                   const bf16_t* __restrict__ K,
                                                   const bf16_t* __restrict__ Vt,
                                                   const int* __restrict__ pos,
                                                   bf16_t* __restrict__ O,
                                                   bf16_t* __restrict__ Opart,
                                                   float* __restrict__ Mst,
                                                   float* __restrict__ Lst) {
  __shared__ bf16_t Ks[2][64 * 64];
  __shared__ bf16_t Vs[2][64 * 64];

  const int t = threadIdx.x;
  const int lane = t & 63, wv = t >> 6;
  const int l31 = lane & 31, hi = lane >> 5;

  const int bid = blockIdx.x;
  const int bh = (bid & 7) * 4 + ((bid >> 3) & 3);
  const int v5 = bid >> 5;
  const int qblk = 15 - (v5 >> 1);
  const int half = v5 & 1;
  const int b = bh >> 4, h = bh & 15;
  const int q0 = qblk * 128;

  const bf16_t* Qb = Q + (size_t)bh * (S_ * HD_);
  const bf16_t* Kb = K + (size_t)bh * (S_ * HD_);
  const bf16_t* Vb = Vt + (size_t)bh * (HD_ * S_);

  const int qrow = q0 + wv * 32 + l31;

  const int prow = pos[b * S_ + qrow];
  int wmin = prow;
#pragma unroll
  for (int off = 1; off < 32; off <<= 1) wmin = min(wmin, __shfl_xor(wmin, off));

  int mp = max(pos[b * S_ + q0 + lane], pos[b * S_ + q0 + 64 + lane]);
#pragma unroll
  for (int off = 1; off < 64; off <<= 1) mp = max(mp, __shfl_xor(mp, off));
  const int nt = min(S_ / KVBLK, (mp >> 6) + 1);

  const int t0 = half * 16;
  const int t1 = min(nt, t0 + 16);
  if (t0 >= t1) return;
  const bool needs_merge = (nt > 16);

  bf16x8 qf[4];
#pragma unroll
  for (int c = 0; c < 4; c++)
    qf[c] = *(const bf16x8*)(Qb + (size_t)qrow * HD_ + c * 16 + hi * 8);

  const int r0 = t >> 3, c0 = t & 7;
  const int r1 = (t + 256) >> 3, c1 = t & 7;
  const bf16_t* KgA = Kb + (size_t)r0 * HD_ + ((c0 ^ (r0 & 7)) * 8);
  const bf16_t* KgB = Kb + (size_t)r1 * HD_ + ((c1 ^ (r1 & 7)) * 8);
  const bf16_t* VgA = Vb + (size_t)r0 * S_ + ((c0 ^ (r0 & 7)) * 8);
  const bf16_t* VgB = Vb + (size_t)r1 * S_ + ((c1 ^ (r1 & 7)) * 8);
  const int ldsA = t * 8, ldsB = (t + 256) * 8;

  f32x16 oT[2];
#pragma unroll
  for (int dt = 0; dt < 2; dt++)
#pragma unroll
    for (int r = 0; r < 16; r++) oT[dt][r] = 0.f;
  float m_run = NINF, l_run = 0.f;

  {
    const int kn = t0 * KVBLK;
    gload_lds16(KgA + (size_t)kn * HD_, Ks[0] + ldsA);
    gload_lds16(KgB + (size_t)kn * HD_, Ks[0] + ldsB);
    gload_lds16(VgA + kn, Vs[0] + ldsA);
    gload_lds16(VgB + kn, Vs[0] + ldsB);
  }
  __syncthreads();

  for (int kt = t0; kt < t1; ++kt) {
    const int k0 = kt * KVBLK;
    const int cur = kt & 1;
    if (kt + 1 < t1) {
      const int kn = (kt + 1) * KVBLK;
      gload_lds16(KgA + (size_t)kn * HD_, Ks[cur ^ 1] + ldsA);
      gload_lds16(KgB + (size_t)kn * HD_, Ks[cur ^ 1] + ldsB);
      gload_lds16(VgA + kn, Vs[cur ^ 1] + ldsA);
      gload_lds16(VgB + kn, Vs[cur ^ 1] + ldsB);
    }
    const bf16_t* Kc = Ks[cur];
    const bf16_t* Vc = Vs[cur];

    f32x16 s0, s1;
#pragma unroll
    for (int r = 0; r < 16; r++) { s0[r] = 0.f; s1[r] = 0.f; }
    __builtin_amdgcn_s_setprio(1);
#pragma unroll
    for (int c = 0; c < 4; c++) {
      const int c2 = c * 2 + hi;
      const int kr0 = l31;
      const int kr1 = 32 + l31;
      bf16x8 kf0 = *(const bf16x8*)(Kc + kr0 * 64 + ((c2 ^ (kr0 & 7)) * 8));
      bf16x8 kf1 = *(const bf16x8*)(Kc + kr1 * 64 + ((c2 ^ (kr1 & 7)) * 8));
      s0 = __builtin_amdgcn_mfma_f32_32x32x16_bf16(kf0, qf[c], s0, 0, 0, 0);
      s1 = __builtin_amdgcn_mfma_f32_32x32x16_bf16(kf1, qf[c], s1, 0, 0, 0);
    }
    __builtin_amdgcn_s_setprio(0);

    float p0[16], p1[16];
    if (k0 + 63 > wmin) {
#pragma unroll
      for (int r = 0; r < 16; r++) {
        int koff = (r & 3) + 8 * (r >> 2) + 4 * hi;
        p0[r] = (k0 + koff <= prow) ? s0[r] : NINF;
        p1[r] = (k0 + 32 + koff <= prow) ? s1[r] : NINF;
      }
    } else {
#pragma unroll
      for (int r = 0; r < 16; r++) { p0[r] = s0[r]; p1[r] = s1[r]; }
    }

    float tm = NINF;
#pragma unroll
    for (int r = 0; r < 16; r++) tm = fmaxf(tm, fmaxf(p0[r], p1[r]));
    tm = fmaxf(tm, __shfl_xor(tm, 32));
    if (__any(tm > m_run + 8.0f)) {
      float mn = fmaxf(fmaxf(m_run, tm), -1e30f);
      float scale = exp2f((m_run - mn) * L2E);
      l_run *= scale;
#pragma unroll
      for (int dt = 0; dt < 2; dt++)
#pragma unroll
        for (int r = 0; r < 16; r++) oT[dt][r] *= scale;
      m_run = mn;
    }
    const float mnl = (m_run == NINF) ? 3.0e38f : m_run * L2E;
    float rs = 0.f;
#pragma unroll
    for (int r = 0; r < 16; r++) {
      p0[r] = exp2f(p0[r] * L2E - mnl);
      p1[r] = exp2f(p1[r] * L2E - mnl);
      rs += p0[r] + p1[r];
    }
    rs += __shfl_xor(rs, 32);
    l_run += rs;

#pragma unroll
    for (int kc = 0; kc < 4; kc++) {
      const float* P = (kc < 2) ? p0 : p1;
      const int rb = (kc & 1) * 8;
      uint32_t xa0 = packbf(P[rb + 0], P[rb + 1]);
      uint32_t xa1 = packbf(P[rb + 2], P[rb + 3]);
      uint32_t xb0 = packbf(P[rb + 4], P[rb + 5]);
      uint32_t xb1 = packbf(P[rb + 6], P[rb + 7]);
      uint32_t sa0 = (uint32_t)__shfl_xor((int)xa0, 32);
      uint32_t sa1 = (uint32_t)__shfl_xor((int)xa1, 32);
      uint32_t sb0 = (uint32_t)__shfl_xor((int)xb0, 32);
      uint32_t sb1 = (uint32_t)__shfl_xor((int)xb1, 32);
      union { uint32_t u[4]; bf16x8 v; } pf;
      pf.u[0] = hi ? sb0 : xa0;
      pf.u[1] = hi ? sb1 : xa1;
      pf.u[2] = hi ? xb0 : sa0;
      pf.u[3] = hi ? xb1 : sa1;
      __builtin_amdgcn_s_setprio(1);
#pragma unroll
      for (int dt = 0; dt < 2; dt++) {
        const int vr = dt * 32 + l31;
        const int c2 = kc * 2 + hi;
        bf16x8 vf = *(const bf16x8*)(Vc + vr * 64 + ((c2 ^ (vr & 7)) * 8));
        oT[dt] = __builtin_amdgcn_mfma_f32_32x32x16_bf16(vf, pf.v, oT[dt], 0, 0, 0);
      }
      __builtin_amdgcn_s_setprio(0);
    }

    __syncthreads();
  }

  const float rl = needs_merge ? 1.0f : ((l_run > 0.f) ? 1.0f / l_run : 0.f);
  bf16_t* Ot = (bf16_t*)Ks + wv * 2048;
#pragma unroll
  for (int dt = 0; dt < 2; dt++)
#pragma unroll
    for (int r = 0; r < 16; r++) {
      int chunk = dt * 4 + (r >> 2);
      int el = (r & 3) + 4 * hi;
      Ot[l31 * 64 + ((chunk ^ (l31 & 7)) * 8) + el] = (__bf16)(oT[dt][r] * rl);
    }
  __syncthreads();
  if (needs_merge) {
    bf16_t* dst = Opart + (((size_t)(half * 32 + bh) * 16 + qblk) * 128) * 64;
#pragma unroll
    for (int it = 0; it < 4; it++) {
      int qr2 = (lane >> 3) + it * 8;
      int cc = lane & 7;
      bf16x8 vv = *(const bf16x8*)(Ot + qr2 * 64 + ((cc ^ (qr2 & 7)) * 8));
      *(bf16x8*)(&dst[(size_t)(wv * 32 + qr2) * 64 + cc * 8]) = vv;
    }
    if (hi == 0) {
      size_t sidx = ((size_t)(half * 32 + bh) * 16 + qblk) * 128 + wv * 32 + l31;
      Mst[sidx] = m_run;
      Lst[sidx] = l_run;
    }
  } else {
#pragma unroll
    for (int it = 0; it < 4; it++) {
      int qr2 = (lane >> 3) + it * 8;
      int cc = lane & 7;
      bf16x8 vv = *(const bf16x8*)(Ot + qr2 * 64 + ((cc ^ (qr2 & 7)) * 8));
      *(bf16x8*)(&O[(size_t)(b * S_ + q0 + wv * 32 + qr2) * D_ + h * 64 + cc * 8]) = vv;
    }
  }
}

// ---------------- split-KV merge ----------------
__global__ __launch_bounds__(256) void attn_merge_kernel(const bf16_t* __restrict__ Opart,
                                                         const float* __restrict__ Mst,
                                                         const float* __restrict__ Lst,
                                                         const int* __restrict__ pos,
                                                         bf16_t* __restrict__ O) {
  __shared__ int wmax_s[4];
  const int t = threadIdx.x;
  const int bid = blockIdx.x;
  const int bh = (bid & 7) * 4 + ((bid >> 3) & 3);
  const int qblk = 15 - (bid >> 5);
  const int b = bh >> 4, h = bh & 15;
  const int q0 = qblk * 128;

  int p = pos[b * S_ + q0 + (t & 127)];
#pragma unroll
  for (int off = 1; off < 64; off <<= 1) p = max(p, __shfl_xor(p, off));
  if ((t & 63) == 0) wmax_s[t >> 6] = p;
  __syncthreads();
  int mp = max(max(wmax_s[0], wmax_s[1]), max(wmax_s[2], wmax_s[3]));
  if ((mp >> 6) + 1 <= 16) return;

  const int r = t >> 1, dh = (t & 1) * 32;
  const size_t s0i = ((size_t)(0 * 32 + bh) * 16 + qblk) * 128 + r;
  const size_t s1i = ((size_t)(1 * 32 + bh) * 16 + qblk) * 128 + r;
  float m0 = Mst[s0i], l0 = Lst[s0i];
  float m1 = Mst[s1i], l1 = Lst[s1i];
  float m = fmaxf(fmaxf(m0, m1), -1e30f);
  float w0 = exp2f((m0 - m) * L2E);
  float w1 = exp2f((m1 - m) * L2E);
  float lt = l0 * w0 + l1 * w1;
  float rl = (lt > 0.f) ? 1.0f / lt : 0.f;
  w0 *= rl; w1 *= rl;
  const bf16_t* pa = Opart + s0i * 64 + dh;
  const bf16_t* pb = Opart + s1i * 64 + dh;
  bf16_t* dst = O + (size_t)(b * S_ + q0 + r) * D_ + h * 64 + dh;
#pragma unroll
  for (int c = 0; c < 4; c++) {
    bf16x8 a = *(const bf16x8*)(pa + c * 8);
    bf16x8 bb = *(const bf16x8*)(pb + c * 8);
    bf16x8 o;
#pragma unroll
    for (int j = 0; j < 8; j++)
      o[j] = (__bf16)((float)a[j] * w0 + (float)bb[j] * w1);
    *(bf16x8*)(dst + c * 8) = o;
  }
}

extern "C" void kernel_launch(void* const* d_in, const int* in_sizes, int n_in,
                              void* d_out, int out_size, void* d_ws, size_t ws_size,
                              hipStream_t stream) {
  const float* inputs = (const float*)d_in[0];
  const int* positions = (const int*)d_in[1];
  const float* W_in = (const float*)d_in[2];
  const float* W_out = (const float*)d_in[3];
  float* out = (float*)d_out;

  bf16_t* X_bf = (bf16_t*)d_ws;
  bf16_t* Win_bf = X_bf + (size_t)4096 * 1024;
  bf16_t* Wout_bf = Win_bf + (size_t)3072 * 1024;
  bf16_t* scratch = Wout_bf + (size_t)1024 * 1024;   // 25.2MB region
  bf16_t* Qb = scratch + (size_t)4096 * 3072;
  bf16_t* Kb = Qb + (size_t)B_ * H_ * S_ * HD_;
  bf16_t* Vtb = Kb + (size_t)B_ * H_ * S_ * HD_;
  bf16_t* Ob = Vtb + (size_t)B_ * H_ * S_ * HD_;

  bf16_t* Opart = scratch;
  float* Mst = (float*)(scratch + (size_t)2 * 32 * 16 * 128 * 64);
  float* Lst = Mst + (size_t)2 * 32 * 16 * 128;

  cast3_bf16_kernel<<<dim3(2048), dim3(256), 0, stream>>>(
      inputs, X_bf, (4096 * 1024) / 4,
      W_in, Win_bf, (3072 * 1024) / 4,
      W_out, Wout_bf, (1024 * 1024) / 4);

  gemm_qkv_rope<<<dim3(16, 12), dim3(512), 0, stream>>>(X_bf, Win_bf, positions, Qb, Kb, Vtb);

  attn_kernel<<<dim3(1024), dim3(256), 0, stream>>>(Qb, Kb, Vtb, positions, Ob, Opart, Mst, Lst);
  attn_merge_kernel<<<dim3(512), dim3(256), 0, stream>>>(Opart, Mst, Lst, positions, Ob);

  gemm_bt<float><<<dim3(32, 8), dim3(256), 0, stream>>>(Ob, Wout_bf, out, 4096, 1024, 1024);
}

// Round 14
// 147.615 us; speedup vs baseline: 1.2213x; 1.2213x over previous
//
#include <hip/hip_runtime.h>
#include <stdint.h>
#include <math.h>

#define B_ 2
#define S_ 2048
#define D_ 1024
#define H_ 16
#define HD_ 64
#define KVBLK 64

typedef __bf16 bf16_t;
typedef __bf16 bf16x4 __attribute__((ext_vector_type(4)));
typedef __bf16 bf16x8 __attribute__((ext_vector_type(8)));
typedef float f32x4 __attribute__((ext_vector_type(4)));
typedef float f32x16 __attribute__((ext_vector_type(16)));
typedef float float4v __attribute__((ext_vector_type(4)));

#define L2E 1.4426950408889634f
#define NINF (-__builtin_inff())

__device__ __forceinline__ void gload_lds16(const bf16_t* g, bf16_t* l) {
  __builtin_amdgcn_global_load_lds((const __attribute__((address_space(1))) void*)g,
                                   (__attribute__((address_space(3))) void*)l, 16, 0, 0);
}

__device__ __forceinline__ uint32_t packbf(float a, float b) {
  union { __bf16 h[2]; uint32_t u; } cvt;
  cvt.h[0] = (__bf16)a; cvt.h[1] = (__bf16)b;
  return cvt.u;
}

// ---------------- fused cast f32 -> bf16 for all three inputs (vector x4) ----------------
__global__ void cast3_bf16_kernel(const float* __restrict__ s0, bf16_t* __restrict__ d0, int n0,
                                  const float* __restrict__ s1, bf16_t* __restrict__ d1, int n1,
                                  const float* __restrict__ s2, bf16_t* __restrict__ d2, int n2) {
  int i = blockIdx.x * blockDim.x + threadIdx.x;
  int stride = gridDim.x * blockDim.x;
  int tot = n0 + n1 + n2;
  for (; i < tot; i += stride) {
    const float* s; bf16_t* d; int j = i;
    if (j < n0) { s = s0; d = d0; }
    else if ((j -= n0) < n1) { s = s1; d = d1; }
    else { j -= n1; s = s2; d = d2; }
    float4v f = *(const float4v*)(s + (size_t)j * 4);
    bf16x4 o;
    o[0] = (__bf16)f[0]; o[1] = (__bf16)f[1]; o[2] = (__bf16)f[2]; o[3] = (__bf16)f[3];
    *(bf16x4*)(d + (size_t)j * 4) = o;
  }
}

// ---------------- small GEMM (128^2, m97 structure) for gemm2 ----------------
template <typename OutT>
__global__ __launch_bounds__(256) void gemm_bt(const bf16_t* __restrict__ A,
                                               const bf16_t* __restrict__ Bm,
                                               OutT* __restrict__ C,
                                               int M, int N, int K) {
  __shared__ bf16_t As[128 * 32];
  __shared__ bf16_t Bs[128 * 32];
  const int t = threadIdx.x;
  const int lane = t & 63, wave = t >> 6;
  const int wr = wave >> 1, wc = wave & 1;
  const int qr = lane & 15, g = lane >> 4;
  const int bm = blockIdx.x, bn = blockIdx.y;

  f32x4 acc[4][4];
#pragma unroll
  for (int m = 0; m < 4; m++)
#pragma unroll
    for (int n = 0; n < 4; n++) acc[m][n] = (f32x4){0.f, 0.f, 0.f, 0.f};

  const bf16_t* Abase = A + (size_t)(bm * 128) * K;
  const bf16_t* Bbase = Bm + (size_t)(bn * 128) * K;
  const int srow = t >> 2;
  const int scol = (t & 3) * 8;

  for (int kk = 0; kk < K; kk += 32) {
    gload_lds16(Abase + (size_t)srow * K + kk + scol,        As + t * 8);
    gload_lds16(Abase + (size_t)(srow + 64) * K + kk + scol, As + 2048 + t * 8);
    gload_lds16(Bbase + (size_t)srow * K + kk + scol,        Bs + t * 8);
    gload_lds16(Bbase + (size_t)(srow + 64) * K + kk + scol, Bs + 2048 + t * 8);
    __syncthreads();
    bf16x8 a[4], b[4];
#pragma unroll
    for (int m = 0; m < 4; m++)
      a[m] = *(const bf16x8*)(As + (wr * 64 + m * 16 + qr) * 32 + g * 8);
#pragma unroll
    for (int n = 0; n < 4; n++)
      b[n] = *(const bf16x8*)(Bs + (wc * 64 + n * 16 + qr) * 32 + g * 8);
#pragma unroll
    for (int m = 0; m < 4; m++)
#pragma unroll
      for (int n = 0; n < 4; n++)
        acc[m][n] = __builtin_amdgcn_mfma_f32_16x16x32_bf16(a[m], b[n], acc[m][n], 0, 0, 0);
    __syncthreads();
  }

#pragma unroll
  for (int m = 0; m < 4; m++) {
    int row0 = bm * 128 + wr * 64 + m * 16 + g * 4;
#pragma unroll
    for (int n = 0; n < 4; n++) {
      int col = bn * 128 + wc * 64 + n * 16 + qr;
#pragma unroll
      for (int r = 0; r < 4; r++)
        C[(size_t)(row0 + r) * N + col] = (OutT)acc[m][n][r];
    }
  }
}

// ---- fused QKV GEMM + RoPE + q-scale + V-transpose: 256^2, BK=64, 8-wave, phase-pipelined ----
// R13 lesson: WRITE_SIZE 170MB was NOT the store pattern (coalesced rewrite didn't move it) --
// it was sincosf: a non-inlined OCML call forcing per-call scratch spill/restore (~1.5KB/thread
// streamed to HBM; scratch reads stay L2-warm, which is why FETCH didn't inflate). Fix: native
// __sinf/__cosf (v_sin_f32/v_cos_f32, inline, no scratch). Angle <= 2047 rad -> native
// reduction error ~1e-4, 40x below bf16 rounding.
__global__ __launch_bounds__(512, 1) void gemm_qkv_rope(const bf16_t* __restrict__ A,
                                                        const bf16_t* __restrict__ Bm,
                                                        const int* __restrict__ pos,
                                                        bf16_t* __restrict__ Qd,
                                                        bf16_t* __restrict__ Kd,
                                                        bf16_t* __restrict__ Vtd) {
  const int K = D_;                 // 1024
  const int NT = K >> 6;
  __shared__ bf16_t As[2][256 * 64];
  __shared__ bf16_t Bs[2][256 * 64];
  const int t = threadIdx.x;
  const int lane = t & 63, wid = t >> 6;
  const int qr = lane & 15, g = lane >> 4;
  const int wm = wid >> 2, wn = wid & 3;
  const int bm = blockIdx.x, bn = blockIdx.y;

  const bf16_t* Ab = A + (size_t)(bm * 256) * K;
  const bf16_t* Bb = Bm + (size_t)(bn * 256) * K;

  const bf16_t* srcA[4];
  const bf16_t* srcB[4];
  int ldsOff[4];
#pragma unroll
  for (int i = 0; i < 4; i++) {
    int e = t + 512 * i;
    int row = e >> 3, cs = e & 7;
    int gcol = (cs ^ (row & 7)) * 8;
    srcA[i] = Ab + (size_t)row * K + gcol;
    srcB[i] = Bb + (size_t)row * K + gcol;
    ldsOff[i] = e * 8;
  }

  f32x4 acc[8][4];
#pragma unroll
  for (int m = 0; m < 8; m++)
#pragma unroll
    for (int n = 0; n < 4; n++) acc[m][n] = (f32x4){0.f, 0.f, 0.f, 0.f};

#define RD(buf_, r_, k_) (*(const bf16x8*)((buf_) + (r_) * 64 + ((((k_) * 4 + g) ^ ((r_) & 7)) * 8)))

#pragma unroll
  for (int i = 0; i < 4; i++) gload_lds16(srcA[i], As[0] + ldsOff[i]);
#pragma unroll
  for (int i = 0; i < 4; i++) gload_lds16(srcB[i], Bs[0] + ldsOff[i]);
#pragma unroll
  for (int i = 0; i < 4; i++) gload_lds16(srcA[i] + 64, As[1] + ldsOff[i]);
#pragma unroll
  for (int i = 0; i < 4; i++) gload_lds16(srcB[i] + 64, Bs[1] + ldsOff[i]);

  for (int T = 0; T < NT; ++T) {
    bf16_t* A_c = As[T & 1];
    bf16_t* B_c = Bs[T & 1];
    if (T + 1 < NT) asm volatile("s_waitcnt vmcnt(8)" ::: "memory");
    else            asm volatile("s_waitcnt vmcnt(0)" ::: "memory");
    __builtin_amdgcn_sched_barrier(0);
    __builtin_amdgcn_s_barrier();

    const bool st = (T + 2 < NT);
    const int kt2 = (T + 2) * 64;

    bf16x8 alo[4][2], ahi[4][2], bfr[4][2];

    // ---- ph0: read a_lo (regions 0,2) + b01; MFMA m0-3 x n0-1 ----
#pragma unroll
    for (int m = 0; m < 4; m++) {
      int r = wm * 128 + m * 16 + qr;
      alo[m][0] = RD(A_c, r, 0); alo[m][1] = RD(A_c, r, 1);
    }
#pragma unroll
    for (int n = 0; n < 2; n++) {
      int r = wn * 64 + n * 16 + qr;
      bfr[n][0] = RD(B_c, r, 0); bfr[n][1] = RD(B_c, r, 1);
    }
    __builtin_amdgcn_s_barrier();
    __builtin_amdgcn_s_setprio(1);
#pragma unroll
    for (int m = 0; m < 4; m++)
#pragma unroll
      for (int n = 0; n < 2; n++)
#pragma unroll
        for (int k = 0; k < 2; k++)
          acc[m][n] = __builtin_amdgcn_mfma_f32_16x16x32_bf16(alo[m][k], bfr[n][k], acc[m][n], 0, 0, 0);
    __builtin_amdgcn_s_setprio(0);
    __builtin_amdgcn_s_barrier();

    // ---- ph1: read b23; stage T+2 A regions {0,2}; MFMA m0-3 x n2-3 ----
#pragma unroll
    for (int n = 2; n < 4; n++) {
      int r = wn * 64 + n * 16 + qr;
      bfr[n][0] = RD(B_c, r, 0); bfr[n][1] = RD(B_c, r, 1);
    }
    if (st) {
      gload_lds16(srcA[0] + kt2, A_c + ldsOff[0]);
      gload_lds16(srcA[2] + kt2, A_c + ldsOff[2]);
    }
    __builtin_amdgcn_s_barrier();
    __builtin_amdgcn_s_setprio(1);
#pragma unroll
    for (int m = 0; m < 4; m++)
#pragma unroll
      for (int n = 2; n < 4; n++)
#pragma unroll
        for (int k = 0; k < 2; k++)
          acc[m][n] = __builtin_amdgcn_mfma_f32_16x16x32_bf16(alo[m][k], bfr[n][k], acc[m][n], 0, 0, 0);
    __builtin_amdgcn_s_setprio(0);
    __builtin_amdgcn_s_barrier();

    // ---- ph2: read a_hi (regions 1,3); stage T+2 B; MFMA m4-7 x n0-1 ----
#pragma unroll
    for (int m = 0; m < 4; m++) {
      int r = wm * 128 + (m + 4) * 16 + qr;
      ahi[m][0] = RD(A_c, r, 0); ahi[m][1] = RD(A_c, r, 1);
    }
    if (st) {
      gload_lds16(srcB[0] + kt2, B_c + ldsOff[0]);
      gload_lds16(srcB[1] + kt2, B_c + ldsOff[1]);
      gload_lds16(srcB[2] + kt2, B_c + ldsOff[2]);
      gload_lds16(srcB[3] + kt2, B_c + ldsOff[3]);
    }
    __builtin_amdgcn_s_barrier();
    __builtin_amdgcn_s_setprio(1);
#pragma unroll
    for (int m = 0; m < 4; m++)
#pragma unroll
      for (int n = 0; n < 2; n++)
#pragma unroll
        for (int k = 0; k < 2; k++)
          acc[m + 4][n] = __builtin_amdgcn_mfma_f32_16x16x32_bf16(ahi[m][k], bfr[n][k], acc[m + 4][n], 0, 0, 0);
    __builtin_amdgcn_s_setprio(0);
    __builtin_amdgcn_s_barrier();

    // ---- ph3: stage T+2 A regions {1,3}; MFMA m4-7 x n2-3 ----
    if (st) {
      gload_lds16(srcA[1] + kt2, A_c + ldsOff[1]);
      gload_lds16(srcA[3] + kt2, A_c + ldsOff[3]);
    }
    __builtin_amdgcn_s_barrier();
    __builtin_amdgcn_s_setprio(1);
#pragma unroll
    for (int m = 0; m < 4; m++)
#pragma unroll
      for (int n = 2; n < 4; n++)
#pragma unroll
        for (int k = 0; k < 2; k++)
          acc[m + 4][n] = __builtin_amdgcn_mfma_f32_16x16x32_bf16(ahi[m][k], bfr[n][k], acc[m + 4][n], 0, 0, 0);
    __builtin_amdgcn_s_setprio(0);
    __builtin_amdgcn_s_barrier();
  }
#undef RD

  // ---- fused epilogue via per-wave LDS staging (coalesced stores) ----
  __syncthreads();  // all waves done with As/Bs (K-loop reads consumed)
  bf16_t* myLds = (wid < 4) ? ((bf16_t*)As + wid * 8192) : ((bf16_t*)Bs + (wid - 4) * 8192);

  const int w = bn * 4 + wn;        // window 0..47
  const int typ = w % 3;            // 0=q, 1=k, 2=v
  const int head = w / 3;
  const int rowbase = bm * 256 + wm * 128;       // multiple of 128 -> single batch
  const int b = rowbase >> 11;
  const int s0w = rowbase & (S_ - 1);

  if (typ == 2) {
    // stage [d][s_local] swizzled: addr = d*128 + ((sc ^ (d&15))*8) + (s&7)
#pragma unroll
    for (int m = 0; m < 8; m++) {
      int sl0 = m * 16 + g * 4;
#pragma unroll
      for (int n = 0; n < 4; n++) {
        int d = n * 16 + qr;
#pragma unroll
        for (int rr = 0; rr < 4; rr++) {
          int sl = sl0 + rr;
          myLds[d * 128 + (((sl >> 3) ^ (d & 15)) * 8) + (sl & 7)] = (__bf16)acc[m][n][rr];
        }
      }
    }
    bf16_t* dstv = Vtd + (size_t)(b * H_ + head) * HD_ * S_ + s0w;
#pragma unroll
    for (int it = 0; it < 16; it++) {
      int d = (lane >> 4) + it * 4;
      int sc = lane & 15;
      bf16x8 v = *(const bf16x8*)(myLds + d * 128 + ((sc ^ (d & 15)) * 8));
      *(bf16x8*)(dstv + (size_t)d * S_ + sc * 8) = v;
    }
  } else {
    // rope + stage [r][d] swizzled: addr = r*64 + ((d>>3 ^ (r&7))*8) + (d&7)
    const float qs = (typ == 0) ? 0.125f : 1.0f;
    const float l2r = 13.287712379549449f / 32.0f;
    float inv[2];
    inv[0] = exp2f(-(float)qr * l2r);
    inv[1] = exp2f(-(float)(qr + 16) * l2r);
#pragma unroll
    for (int m = 0; m < 8; m++) {
      int r0 = m * 16 + g * 4;
#pragma unroll
      for (int rr = 0; rr < 4; rr++) {
        int r = r0 + rr;
        float p = (float)pos[rowbase + r];
#pragma unroll
        for (int n = 0; n < 2; n++) {
          float ang = p * inv[n];
          float sn = __sinf(ang);     // native v_sin_f32 (inline, no scratch)
          float cs = __cosf(ang);     // native v_cos_f32
          float x1 = acc[m][n][rr], x2 = acc[m][n + 2][rr];
          float o1 = (x1 * cs - x2 * sn) * qs;
          float o2 = (x2 * cs + x1 * sn) * qs;
          int d1 = n * 16 + qr, d2 = d1 + 32;
          myLds[r * 64 + (((d1 >> 3) ^ (r & 7)) * 8) + (d1 & 7)] = (__bf16)o1;
          myLds[r * 64 + (((d2 >> 3) ^ (r & 7)) * 8) + (d2 & 7)] = (__bf16)o2;
        }
      }
    }
    bf16_t* dstb = ((typ == 0) ? Qd : Kd) + (size_t)(b * H_ + head) * S_ * HD_ + (size_t)s0w * HD_;
#pragma unroll
    for (int it = 0; it < 16; it++) {
      int r = (lane >> 3) + it * 8;
      int cc = lane & 7;
      bf16x8 v = *(const bf16x8*)(myLds + r * 64 + ((cc ^ (r & 7)) * 8));
      *(bf16x8*)(dstb + (size_t)r * HD_ + cc * 8) = v;
    }
  }
}

// ---------------- flash attention: split-KV (2 halves) + XCD-resident KV mapping ----------------
__global__ __launch_bounds__(256) void attn_kernel(const bf16_t* __restrict__ Q,
                                                   const bf16_t* __restrict__ K,
                                                   const bf16_t* __restrict__ Vt,
                                                   const int* __restrict__ pos,
                                                   bf16_t* __restrict__ O,
                                                   bf16_t* __restrict__ Opart,
                                                   float* __restrict__ Mst,
                                                   float* __restrict__ Lst) {
  __shared__ bf16_t Ks[2][64 * 64];
  __shared__ bf16_t Vs[2][64 * 64];

  const int t = threadIdx.x;
  const int lane = t & 63, wv = t >> 6;
  const int l31 = lane & 31, hi = lane >> 5;

  const int bid = blockIdx.x;
  const int bh = (bid & 7) * 4 + ((bid >> 3) & 3);
  const int v5 = bid >> 5;
  const int qblk = 15 - (v5 >> 1);
  const int half = v5 & 1;
  const int b = bh >> 4, h = bh & 15;
  const int q0 = qblk * 128;

  const bf16_t* Qb = Q + (size_t)bh * (S_ * HD_);
  const bf16_t* Kb = K + (size_t)bh * (S_ * HD_);
  const bf16_t* Vb = Vt + (size_t)bh * (HD_ * S_);

  const int qrow = q0 + wv * 32 + l31;

  const int prow = pos[b * S_ + qrow];
  int wmin = prow;
#pragma unroll
  for (int off = 1; off < 32; off <<= 1) wmin = min(wmin, __shfl_xor(wmin, off));

  int mp = max(pos[b * S_ + q0 + lane], pos[b * S_ + q0 + 64 + lane]);
#pragma unroll
  for (int off = 1; off < 64; off <<= 1) mp = max(mp, __shfl_xor(mp, off));
  const int nt = min(S_ / KVBLK, (mp >> 6) + 1);

  const int t0 = half * 16;
  const int t1 = min(nt, t0 + 16);
  if (t0 >= t1) return;
  const bool needs_merge = (nt > 16);

  bf16x8 qf[4];
#pragma unroll
  for (int c = 0; c < 4; c++)
    qf[c] = *(const bf16x8*)(Qb + (size_t)qrow * HD_ + c * 16 + hi * 8);

  const int r0 = t >> 3, c0 = t & 7;
  const int r1 = (t + 256) >> 3, c1 = t & 7;
  const bf16_t* KgA = Kb + (size_t)r0 * HD_ + ((c0 ^ (r0 & 7)) * 8);
  const bf16_t* KgB = Kb + (size_t)r1 * HD_ + ((c1 ^ (r1 & 7)) * 8);
  const bf16_t* VgA = Vb + (size_t)r0 * S_ + ((c0 ^ (r0 & 7)) * 8);
  const bf16_t* VgB = Vb + (size_t)r1 * S_ + ((c1 ^ (r1 & 7)) * 8);
  const int ldsA = t * 8, ldsB = (t + 256) * 8;

  f32x16 oT[2];
#pragma unroll
  for (int dt = 0; dt < 2; dt++)
#pragma unroll
    for (int r = 0; r < 16; r++) oT[dt][r] = 0.f;
  float m_run = NINF, l_run = 0.f;

  {
    const int kn = t0 * KVBLK;
    gload_lds16(KgA + (size_t)kn * HD_, Ks[0] + ldsA);
    gload_lds16(KgB + (size_t)kn * HD_, Ks[0] + ldsB);
    gload_lds16(VgA + kn, Vs[0] + ldsA);
    gload_lds16(VgB + kn, Vs[0] + ldsB);
  }
  __syncthreads();

  for (int kt = t0; kt < t1; ++kt) {
    const int k0 = kt * KVBLK;
    const int cur = kt & 1;
    if (kt + 1 < t1) {
      const int kn = (kt + 1) * KVBLK;
      gload_lds16(KgA + (size_t)kn * HD_, Ks[cur ^ 1] + ldsA);
      gload_lds16(KgB + (size_t)kn * HD_, Ks[cur ^ 1] + ldsB);
      gload_lds16(VgA + kn, Vs[cur ^ 1] + ldsA);
      gload_lds16(VgB + kn, Vs[cur ^ 1] + ldsB);
    }
    const bf16_t* Kc = Ks[cur];
    const bf16_t* Vc = Vs[cur];

    f32x16 s0, s1;
#pragma unroll
    for (int r = 0; r < 16; r++) { s0[r] = 0.f; s1[r] = 0.f; }
    __builtin_amdgcn_s_setprio(1);
#pragma unroll
    for (int c = 0; c < 4; c++) {
      const int c2 = c * 2 + hi;
      const int kr0 = l31;
      const int kr1 = 32 + l31;
      bf16x8 kf0 = *(const bf16x8*)(Kc + kr0 * 64 + ((c2 ^ (kr0 & 7)) * 8));
      bf16x8 kf1 = *(const bf16x8*)(Kc + kr1 * 64 + ((c2 ^ (kr1 & 7)) * 8));
      s0 = __builtin_amdgcn_mfma_f32_32x32x16_bf16(kf0, qf[c], s0, 0, 0, 0);
      s1 = __builtin_amdgcn_mfma_f32_32x32x16_bf16(kf1, qf[c], s1, 0, 0, 0);
    }
    __builtin_amdgcn_s_setprio(0);

    float p0[16], p1[16];
    if (k0 + 63 > wmin) {
#pragma unroll
      for (int r = 0; r < 16; r++) {
        int koff = (r & 3) + 8 * (r >> 2) + 4 * hi;
        p0[r] = (k0 + koff <= prow) ? s0[r] : NINF;
        p1[r] = (k0 + 32 + koff <= prow) ? s1[r] : NINF;
      }
    } else {
#pragma unroll
      for (int r = 0; r < 16; r++) { p0[r] = s0[r]; p1[r] = s1[r]; }
    }

    float tm = NINF;
#pragma unroll
    for (int r = 0; r < 16; r++) tm = fmaxf(tm, fmaxf(p0[r], p1[r]));
    tm = fmaxf(tm, __shfl_xor(tm, 32));
    if (__any(tm > m_run + 8.0f)) {
      float mn = fmaxf(fmaxf(m_run, tm), -1e30f);
      float scale = exp2f((m_run - mn) * L2E);
      l_run *= scale;
#pragma unroll
      for (int dt = 0; dt < 2; dt++)
#pragma unroll
        for (int r = 0; r < 16; r++) oT[dt][r] *= scale;
      m_run = mn;
    }
    const float mnl = (m_run == NINF) ? 3.0e38f : m_run * L2E;
    float rs = 0.f;
#pragma unroll
    for (int r = 0; r < 16; r++) {
      p0[r] = exp2f(p0[r] * L2E - mnl);
      p1[r] = exp2f(p1[r] * L2E - mnl);
      rs += p0[r] + p1[r];
    }
    rs += __shfl_xor(rs, 32);
    l_run += rs;

#pragma unroll
    for (int kc = 0; kc < 4; kc++) {
      const float* P = (kc < 2) ? p0 : p1;
      const int rb = (kc & 1) * 8;
      uint32_t xa0 = packbf(P[rb + 0], P[rb + 1]);
      uint32_t xa1 = packbf(P[rb + 2], P[rb + 3]);
      uint32_t xb0 = packbf(P[rb + 4], P[rb + 5]);
      uint32_t xb1 = packbf(P[rb + 6], P[rb + 7]);
      uint32_t sa0 = (uint32_t)__shfl_xor((int)xa0, 32);
      uint32_t sa1 = (uint32_t)__shfl_xor((int)xa1, 32);
      uint32_t sb0 = (uint32_t)__shfl_xor((int)xb0, 32);
      uint32_t sb1 = (uint32_t)__shfl_xor((int)xb1, 32);
      union { uint32_t u[4]; bf16x8 v; } pf;
      pf.u[0] = hi ? sb0 : xa0;
      pf.u[1] = hi ? sb1 : xa1;
      pf.u[2] = hi ? xb0 : sa0;
      pf.u[3] = hi ? xb1 : sa1;
      __builtin_amdgcn_s_setprio(1);
#pragma unroll
      for (int dt = 0; dt < 2; dt++) {
        const int vr = dt * 32 + l31;
        const int c2 = kc * 2 + hi;
        bf16x8 vf = *(const bf16x8*)(Vc + vr * 64 + ((c2 ^ (vr & 7)) * 8));
        oT[dt] = __builtin_amdgcn_mfma_f32_32x32x16_bf16(vf, pf.v, oT[dt], 0, 0, 0);
      }
      __builtin_amdgcn_s_setprio(0);
    }

    __syncthreads();
  }

  const float rl = needs_merge ? 1.0f : ((l_run > 0.f) ? 1.0f / l_run : 0.f);
  bf16_t* Ot = (bf16_t*)Ks + wv * 2048;
#pragma unroll
  for (int dt = 0; dt < 2; dt++)
#pragma unroll
    for (int r = 0; r < 16; r++) {
      int chunk = dt * 4 + (r >> 2);
      int el = (r & 3) + 4 * hi;
      Ot[l31 * 64 + ((chunk ^ (l31 & 7)) * 8) + el] = (__bf16)(oT[dt][r] * rl);
    }
  __syncthreads();
  if (needs_merge) {
    bf16_t* dst = Opart + (((size_t)(half * 32 + bh) * 16 + qblk) * 128) * 64;
#pragma unroll
    for (int it = 0; it < 4; it++) {
      int qr2 = (lane >> 3) + it * 8;
      int cc = lane & 7;
      bf16x8 vv = *(const bf16x8*)(Ot + qr2 * 64 + ((cc ^ (qr2 & 7)) * 8));
      *(bf16x8*)(&dst[(size_t)(wv * 32 + qr2) * 64 + cc * 8]) = vv;
    }
    if (hi == 0) {
      size_t sidx = ((size_t)(half * 32 + bh) * 16 + qblk) * 128 + wv * 32 + l31;
      Mst[sidx] = m_run;
      Lst[sidx] = l_run;
    }
  } else {
#pragma unroll
    for (int it = 0; it < 4; it++) {
      int qr2 = (lane >> 3) + it * 8;
      int cc = lane & 7;
      bf16x8 vv = *(const bf16x8*)(Ot + qr2 * 64 + ((cc ^ (qr2 & 7)) * 8));
      *(bf16x8*)(&O[(size_t)(b * S_ + q0 + wv * 32 + qr2) * D_ + h * 64 + cc * 8]) = vv;
    }
  }
}

// ---------------- split-KV merge ----------------
__global__ __launch_bounds__(256) void attn_merge_kernel(const bf16_t* __restrict__ Opart,
                                                         const float* __restrict__ Mst,
                                                         const float* __restrict__ Lst,
                                                         const int* __restrict__ pos,
                                                         bf16_t* __restrict__ O) {
  __shared__ int wmax_s[4];
  const int t = threadIdx.x;
  const int bid = blockIdx.x;
  const int bh = (bid & 7) * 4 + ((bid >> 3) & 3);
  const int qblk = 15 - (bid >> 5);
  const int b = bh >> 4, h = bh & 15;
  const int q0 = qblk * 128;

  int p = pos[b * S_ + q0 + (t & 127)];
#pragma unroll
  for (int off = 1; off < 64; off <<= 1) p = max(p, __shfl_xor(p, off));
  if ((t & 63) == 0) wmax_s[t >> 6] = p;
  __syncthreads();
  int mp = max(max(wmax_s[0], wmax_s[1]), max(wmax_s[2], wmax_s[3]));
  if ((mp >> 6) + 1 <= 16) return;

  const int r = t >> 1, dh = (t & 1) * 32;
  const size_t s0i = ((size_t)(0 * 32 + bh) * 16 + qblk) * 128 + r;
  const size_t s1i = ((size_t)(1 * 32 + bh) * 16 + qblk) * 128 + r;
  float m0 = Mst[s0i], l0 = Lst[s0i];
  float m1 = Mst[s1i], l1 = Lst[s1i];
  float m = fmaxf(fmaxf(m0, m1), -1e30f);
  float w0 = exp2f((m0 - m) * L2E);
  float w1 = exp2f((m1 - m) * L2E);
  float lt = l0 * w0 + l1 * w1;
  float rl = (lt > 0.f) ? 1.0f / lt : 0.f;
  w0 *= rl; w1 *= rl;
  const bf16_t* pa = Opart + s0i * 64 + dh;
  const bf16_t* pb = Opart + s1i * 64 + dh;
  bf16_t* dst = O + (size_t)(b * S_ + q0 + r) * D_ + h * 64 + dh;
#pragma unroll
  for (int c = 0; c < 4; c++) {
    bf16x8 a = *(const bf16x8*)(pa + c * 8);
    bf16x8 bb = *(const bf16x8*)(pb + c * 8);
    bf16x8 o;
#pragma unroll
    for (int j = 0; j < 8; j++)
      o[j] = (__bf16)((float)a[j] * w0 + (float)bb[j] * w1);
    *(bf16x8*)(dst + c * 8) = o;
  }
}

extern "C" void kernel_launch(void* const* d_in, const int* in_sizes, int n_in,
                              void* d_out, int out_size, void* d_ws, size_t ws_size,
                              hipStream_t stream) {
  const float* inputs = (const float*)d_in[0];
  const int* positions = (const int*)d_in[1];
  const float* W_in = (const float*)d_in[2];
  const float* W_out = (const float*)d_in[3];
  float* out = (float*)d_out;

  bf16_t* X_bf = (bf16_t*)d_ws;
  bf16_t* Win_bf = X_bf + (size_t)4096 * 1024;
  bf16_t* Wout_bf = Win_bf + (size_t)3072 * 1024;
  bf16_t* scratch = Wout_bf + (size_t)1024 * 1024;   // 25.2MB region
  bf16_t* Qb = scratch + (size_t)4096 * 3072;
  bf16_t* Kb = Qb + (size_t)B_ * H_ * S_ * HD_;
  bf16_t* Vtb = Kb + (size_t)B_ * H_ * S_ * HD_;
  bf16_t* Ob = Vtb + (size_t)B_ * H_ * S_ * HD_;

  bf16_t* Opart = scratch;
  float* Mst = (float*)(scratch + (size_t)2 * 32 * 16 * 128 * 64);
  float* Lst = Mst + (size_t)2 * 32 * 16 * 128;

  cast3_bf16_kernel<<<dim3(2048), dim3(256), 0, stream>>>(
      inputs, X_bf, (4096 * 1024) / 4,
      W_in, Win_bf, (3072 * 1024) / 4,
      W_out, Wout_bf, (1024 * 1024) / 4);

  gemm_qkv_rope<<<dim3(16, 12), dim3(512), 0, stream>>>(X_bf, Win_bf, positions, Qb, Kb, Vtb);

  attn_kernel<<<dim3(1024), dim3(256), 0, stream>>>(Qb, Kb, Vtb, positions, Ob, Opart, Mst, Lst);
  attn_merge_kernel<<<dim3(512), dim3(256), 0, stream>>>(Opart, Mst, Lst, positions, Ob);

  gemm_bt<float><<<dim3(32, 8), dim3(256), 0, stream>>>(Ob, Wout_bf, out, 4096, 1024, 1024);
}

// Round 15
// 141.373 us; speedup vs baseline: 1.2752x; 1.0442x over previous
//
#include <hip/hip_runtime.h>
#include <stdint.h>
#include <math.h>

#define B_ 2
#define S_ 2048
#define D_ 1024
#define H_ 16
#define HD_ 64
#define KVBLK 64
#define CHTILES 8                 // kv tiles per split chunk
#define CHELEMS ((size_t)32 * 16 * 128 * 64)   // bf16 elems per chunk partial

typedef __bf16 bf16_t;
typedef __bf16 bf16x4 __attribute__((ext_vector_type(4)));
typedef __bf16 bf16x8 __attribute__((ext_vector_type(8)));
typedef float f32x4 __attribute__((ext_vector_type(4)));
typedef float f32x16 __attribute__((ext_vector_type(16)));
typedef float float4v __attribute__((ext_vector_type(4)));

#define L2E 1.4426950408889634f
#define NINF (-__builtin_inff())

__device__ __forceinline__ void gload_lds16(const bf16_t* g, bf16_t* l) {
  __builtin_amdgcn_global_load_lds((const __attribute__((address_space(1))) void*)g,
                                   (__attribute__((address_space(3))) void*)l, 16, 0, 0);
}

__device__ __forceinline__ uint32_t packbf(float a, float b) {
  union { __bf16 h[2]; uint32_t u; } cvt;
  cvt.h[0] = (__bf16)a; cvt.h[1] = (__bf16)b;
  return cvt.u;
}

// ---------------- fused cast f32 -> bf16 for all three inputs (vector x4) ----------------
__global__ void cast3_bf16_kernel(const float* __restrict__ s0, bf16_t* __restrict__ d0, int n0,
                                  const float* __restrict__ s1, bf16_t* __restrict__ d1, int n1,
                                  const float* __restrict__ s2, bf16_t* __restrict__ d2, int n2) {
  int i = blockIdx.x * blockDim.x + threadIdx.x;
  int stride = gridDim.x * blockDim.x;
  int tot = n0 + n1 + n2;
  for (; i < tot; i += stride) {
    const float* s; bf16_t* d; int j = i;
    if (j < n0) { s = s0; d = d0; }
    else if ((j -= n0) < n1) { s = s1; d = d1; }
    else { j -= n1; s = s2; d = d2; }
    float4v f = *(const float4v*)(s + (size_t)j * 4);
    bf16x4 o;
    o[0] = (__bf16)f[0]; o[1] = (__bf16)f[1]; o[2] = (__bf16)f[2]; o[3] = (__bf16)f[3];
    *(bf16x4*)(d + (size_t)j * 4) = o;
  }
}

// ---------------- small GEMM (128^2, m97 structure) for gemm2 ----------------
template <typename OutT>
__global__ __launch_bounds__(256) void gemm_bt(const bf16_t* __restrict__ A,
                                               const bf16_t* __restrict__ Bm,
                                               OutT* __restrict__ C,
                                               int M, int N, int K) {
  __shared__ bf16_t As[128 * 32];
  __shared__ bf16_t Bs[128 * 32];
  const int t = threadIdx.x;
  const int lane = t & 63, wave = t >> 6;
  const int wr = wave >> 1, wc = wave & 1;
  const int qr = lane & 15, g = lane >> 4;
  const int bm = blockIdx.x, bn = blockIdx.y;

  f32x4 acc[4][4];
#pragma unroll
  for (int m = 0; m < 4; m++)
#pragma unroll
    for (int n = 0; n < 4; n++) acc[m][n] = (f32x4){0.f, 0.f, 0.f, 0.f};

  const bf16_t* Abase = A + (size_t)(bm * 128) * K;
  const bf16_t* Bbase = Bm + (size_t)(bn * 128) * K;
  const int srow = t >> 2;
  const int scol = (t & 3) * 8;

  for (int kk = 0; kk < K; kk += 32) {
    gload_lds16(Abase + (size_t)srow * K + kk + scol,        As + t * 8);
    gload_lds16(Abase + (size_t)(srow + 64) * K + kk + scol, As + 2048 + t * 8);
    gload_lds16(Bbase + (size_t)srow * K + kk + scol,        Bs + t * 8);
    gload_lds16(Bbase + (size_t)(srow + 64) * K + kk + scol, Bs + 2048 + t * 8);
    __syncthreads();
    bf16x8 a[4], b[4];
#pragma unroll
    for (int m = 0; m < 4; m++)
      a[m] = *(const bf16x8*)(As + (wr * 64 + m * 16 + qr) * 32 + g * 8);
#pragma unroll
    for (int n = 0; n < 4; n++)
      b[n] = *(const bf16x8*)(Bs + (wc * 64 + n * 16 + qr) * 32 + g * 8);
#pragma unroll
    for (int m = 0; m < 4; m++)
#pragma unroll
      for (int n = 0; n < 4; n++)
        acc[m][n] = __builtin_amdgcn_mfma_f32_16x16x32_bf16(a[m], b[n], acc[m][n], 0, 0, 0);
    __syncthreads();
  }

#pragma unroll
  for (int m = 0; m < 4; m++) {
    int row0 = bm * 128 + wr * 64 + m * 16 + g * 4;
#pragma unroll
    for (int n = 0; n < 4; n++) {
      int col = bn * 128 + wc * 64 + n * 16 + qr;
#pragma unroll
      for (int r = 0; r < 4; r++)
        C[(size_t)(row0 + r) * N + col] = (OutT)acc[m][n][r];
    }
  }
}

// ---- fused QKV GEMM + RoPE + q-scale + V-transpose (R14-proven; native __sinf/__cosf) ----
__global__ __launch_bounds__(512, 1) void gemm_qkv_rope(const bf16_t* __restrict__ A,
                                                        const bf16_t* __restrict__ Bm,
                                                        const int* __restrict__ pos,
                                                        bf16_t* __restrict__ Qd,
                                                        bf16_t* __restrict__ Kd,
                                                        bf16_t* __restrict__ Vtd) {
  const int K = D_;
  const int NT = K >> 6;
  __shared__ bf16_t As[2][256 * 64];
  __shared__ bf16_t Bs[2][256 * 64];
  const int t = threadIdx.x;
  const int lane = t & 63, wid = t >> 6;
  const int qr = lane & 15, g = lane >> 4;
  const int wm = wid >> 2, wn = wid & 3;
  const int bm = blockIdx.x, bn = blockIdx.y;

  const bf16_t* Ab = A + (size_t)(bm * 256) * K;
  const bf16_t* Bb = Bm + (size_t)(bn * 256) * K;

  const bf16_t* srcA[4];
  const bf16_t* srcB[4];
  int ldsOff[4];
#pragma unroll
  for (int i = 0; i < 4; i++) {
    int e = t + 512 * i;
    int row = e >> 3, cs = e & 7;
    int gcol = (cs ^ (row & 7)) * 8;
    srcA[i] = Ab + (size_t)row * K + gcol;
    srcB[i] = Bb + (size_t)row * K + gcol;
    ldsOff[i] = e * 8;
  }

  f32x4 acc[8][4];
#pragma unroll
  for (int m = 0; m < 8; m++)
#pragma unroll
    for (int n = 0; n < 4; n++) acc[m][n] = (f32x4){0.f, 0.f, 0.f, 0.f};

#define RD(buf_, r_, k_) (*(const bf16x8*)((buf_) + (r_) * 64 + ((((k_) * 4 + g) ^ ((r_) & 7)) * 8)))

#pragma unroll
  for (int i = 0; i < 4; i++) gload_lds16(srcA[i], As[0] + ldsOff[i]);
#pragma unroll
  for (int i = 0; i < 4; i++) gload_lds16(srcB[i], Bs[0] + ldsOff[i]);
#pragma unroll
  for (int i = 0; i < 4; i++) gload_lds16(srcA[i] + 64, As[1] + ldsOff[i]);
#pragma unroll
  for (int i = 0; i < 4; i++) gload_lds16(srcB[i] + 64, Bs[1] + ldsOff[i]);

  for (int T = 0; T < NT; ++T) {
    bf16_t* A_c = As[T & 1];
    bf16_t* B_c = Bs[T & 1];
    if (T + 1 < NT) asm volatile("s_waitcnt vmcnt(8)" ::: "memory");
    else            asm volatile("s_waitcnt vmcnt(0)" ::: "memory");
    __builtin_amdgcn_sched_barrier(0);
    __builtin_amdgcn_s_barrier();

    const bool st = (T + 2 < NT);
    const int kt2 = (T + 2) * 64;

    bf16x8 alo[4][2], ahi[4][2], bfr[4][2];

    // ---- ph0 ----
#pragma unroll
    for (int m = 0; m < 4; m++) {
      int r = wm * 128 + m * 16 + qr;
      alo[m][0] = RD(A_c, r, 0); alo[m][1] = RD(A_c, r, 1);
    }
#pragma unroll
    for (int n = 0; n < 2; n++) {
      int r = wn * 64 + n * 16 + qr;
      bfr[n][0] = RD(B_c, r, 0); bfr[n][1] = RD(B_c, r, 1);
    }
    __builtin_amdgcn_s_barrier();
    __builtin_amdgcn_s_setprio(1);
#pragma unroll
    for (int m = 0; m < 4; m++)
#pragma unroll
      for (int n = 0; n < 2; n++)
#pragma unroll
        for (int k = 0; k < 2; k++)
          acc[m][n] = __builtin_amdgcn_mfma_f32_16x16x32_bf16(alo[m][k], bfr[n][k], acc[m][n], 0, 0, 0);
    __builtin_amdgcn_s_setprio(0);
    __builtin_amdgcn_s_barrier();

    // ---- ph1 ----
#pragma unroll
    for (int n = 2; n < 4; n++) {
      int r = wn * 64 + n * 16 + qr;
      bfr[n][0] = RD(B_c, r, 0); bfr[n][1] = RD(B_c, r, 1);
    }
    if (st) {
      gload_lds16(srcA[0] + kt2, A_c + ldsOff[0]);
      gload_lds16(srcA[2] + kt2, A_c + ldsOff[2]);
    }
    __builtin_amdgcn_s_barrier();
    __builtin_amdgcn_s_setprio(1);
#pragma unroll
    for (int m = 0; m < 4; m++)
#pragma unroll
      for (int n = 2; n < 4; n++)
#pragma unroll
        for (int k = 0; k < 2; k++)
          acc[m][n] = __builtin_amdgcn_mfma_f32_16x16x32_bf16(alo[m][k], bfr[n][k], acc[m][n], 0, 0, 0);
    __builtin_amdgcn_s_setprio(0);
    __builtin_amdgcn_s_barrier();

    // ---- ph2 ----
#pragma unroll
    for (int m = 0; m < 4; m++) {
      int r = wm * 128 + (m + 4) * 16 + qr;
      ahi[m][0] = RD(A_c, r, 0); ahi[m][1] = RD(A_c, r, 1);
    }
    if (st) {
      gload_lds16(srcB[0] + kt2, B_c + ldsOff[0]);
      gload_lds16(srcB[1] + kt2, B_c + ldsOff[1]);
      gload_lds16(srcB[2] + kt2, B_c + ldsOff[2]);
      gload_lds16(srcB[3] + kt2, B_c + ldsOff[3]);
    }
    __builtin_amdgcn_s_barrier();
    __builtin_amdgcn_s_setprio(1);
#pragma unroll
    for (int m = 0; m < 4; m++)
#pragma unroll
      for (int n = 0; n < 2; n++)
#pragma unroll
        for (int k = 0; k < 2; k++)
          acc[m + 4][n] = __builtin_amdgcn_mfma_f32_16x16x32_bf16(ahi[m][k], bfr[n][k], acc[m + 4][n], 0, 0, 0);
    __builtin_amdgcn_s_setprio(0);
    __builtin_amdgcn_s_barrier();

    // ---- ph3 ----
    if (st) {
      gload_lds16(srcA[1] + kt2, A_c + ldsOff[1]);
      gload_lds16(srcA[3] + kt2, A_c + ldsOff[3]);
    }
    __builtin_amdgcn_s_barrier();
    __builtin_amdgcn_s_setprio(1);
#pragma unroll
    for (int m = 0; m < 4; m++)
#pragma unroll
      for (int n = 2; n < 4; n++)
#pragma unroll
        for (int k = 0; k < 2; k++)
          acc[m + 4][n] = __builtin_amdgcn_mfma_f32_16x16x32_bf16(ahi[m][k], bfr[n][k], acc[m + 4][n], 0, 0, 0);
    __builtin_amdgcn_s_setprio(0);
    __builtin_amdgcn_s_barrier();
  }
#undef RD

  // ---- fused epilogue via per-wave LDS staging (coalesced stores) ----
  __syncthreads();
  bf16_t* myLds = (wid < 4) ? ((bf16_t*)As + wid * 8192) : ((bf16_t*)Bs + (wid - 4) * 8192);

  const int w = bn * 4 + wn;
  const int typ = w % 3;
  const int head = w / 3;
  const int rowbase = bm * 256 + wm * 128;
  const int b = rowbase >> 11;
  const int s0w = rowbase & (S_ - 1);

  if (typ == 2) {
#pragma unroll
    for (int m = 0; m < 8; m++) {
      int sl0 = m * 16 + g * 4;
#pragma unroll
      for (int n = 0; n < 4; n++) {
        int d = n * 16 + qr;
#pragma unroll
        for (int rr = 0; rr < 4; rr++) {
          int sl = sl0 + rr;
          myLds[d * 128 + (((sl >> 3) ^ (d & 15)) * 8) + (sl & 7)] = (__bf16)acc[m][n][rr];
        }
      }
    }
    bf16_t* dstv = Vtd + (size_t)(b * H_ + head) * HD_ * S_ + s0w;
#pragma unroll
    for (int it = 0; it < 16; it++) {
      int d = (lane >> 4) + it * 4;
      int sc = lane & 15;
      bf16x8 v = *(const bf16x8*)(myLds + d * 128 + ((sc ^ (d & 15)) * 8));
      *(bf16x8*)(dstv + (size_t)d * S_ + sc * 8) = v;
    }
  } else {
    const float qs = (typ == 0) ? 0.125f : 1.0f;
    const float l2r = 13.287712379549449f / 32.0f;
    float inv[2];
    inv[0] = exp2f(-(float)qr * l2r);
    inv[1] = exp2f(-(float)(qr + 16) * l2r);
#pragma unroll
    for (int m = 0; m < 8; m++) {
      int r0 = m * 16 + g * 4;
#pragma unroll
      for (int rr = 0; rr < 4; rr++) {
        int r = r0 + rr;
        float p = (float)pos[rowbase + r];
#pragma unroll
        for (int n = 0; n < 2; n++) {
          float ang = p * inv[n];
          float sn = __sinf(ang);
          float cs = __cosf(ang);
          float x1 = acc[m][n][rr], x2 = acc[m][n + 2][rr];
          float o1 = (x1 * cs - x2 * sn) * qs;
          float o2 = (x2 * cs + x1 * sn) * qs;
          int d1 = n * 16 + qr, d2 = d1 + 32;
          myLds[r * 64 + (((d1 >> 3) ^ (r & 7)) * 8) + (d1 & 7)] = (__bf16)o1;
          myLds[r * 64 + (((d2 >> 3) ^ (r & 7)) * 8) + (d2 & 7)] = (__bf16)o2;
        }
      }
    }
    bf16_t* dstb = ((typ == 0) ? Qd : Kd) + (size_t)(b * H_ + head) * S_ * HD_ + (size_t)s0w * HD_;
#pragma unroll
    for (int it = 0; it < 16; it++) {
      int r = (lane >> 3) + it * 8;
      int cc = lane & 7;
      bf16x8 v = *(const bf16x8*)(myLds + r * 64 + ((cc ^ (r & 7)) * 8));
      *(bf16x8*)(dstb + (size_t)r * HD_ + cc * 8) = v;
    }
  }
}

// ---------------- flash attention: split-KV x4 chunks + XCD-resident KV mapping ----------------
// Grid 2048: bid = [v:6][bhsub:2][xcd:3]; bh=(bid&7)*4+((bid>>3)&3); v=bid>>5:
// qblk = 15-(v>>2) (heavy first), chunk = v&3. Chunk covers tiles [chunk*8, min(nt, chunk*8+8)).
// nt<=8: chunk0 writes final O directly (chunks 1-3 exit). nt>8: active chunks write
// unnormalized bf16 partial O + (m,l); merge combines nch=ceil(nt/8) chunks.
// Partials: chunks 0-2 in dead qkv-scratch (exact fit), chunk 3 in dead X_bf (exact fit),
// stats in dead Win_bf -- no new memory assumptions; all rewritten every launch.
__global__ __launch_bounds__(256) void attn_kernel(const bf16_t* __restrict__ Q,
                                                   const bf16_t* __restrict__ K,
                                                   const bf16_t* __restrict__ Vt,
                                                   const int* __restrict__ pos,
                                                   bf16_t* __restrict__ O,
                                                   bf16_t* __restrict__ Op0,
                                                   bf16_t* __restrict__ Op3,
                                                   float* __restrict__ Mst,
                                                   float* __restrict__ Lst) {
  __shared__ bf16_t Ks[2][64 * 64];
  __shared__ bf16_t Vs[2][64 * 64];

  const int t = threadIdx.x;
  const int lane = t & 63, wv = t >> 6;
  const int l31 = lane & 31, hi = lane >> 5;

  const int bid = blockIdx.x;
  const int bh = (bid & 7) * 4 + ((bid >> 3) & 3);
  const int v6 = bid >> 5;
  const int qblk = 15 - (v6 >> 2);
  const int chunk = v6 & 3;
  const int b = bh >> 4, h = bh & 15;
  const int q0 = qblk * 128;

  const bf16_t* Qb = Q + (size_t)bh * (S_ * HD_);
  const bf16_t* Kb = K + (size_t)bh * (S_ * HD_);
  const bf16_t* Vb = Vt + (size_t)bh * (HD_ * S_);

  const int qrow = q0 + wv * 32 + l31;

  const int prow = pos[b * S_ + qrow];
  int wmin = prow;
#pragma unroll
  for (int off = 1; off < 32; off <<= 1) wmin = min(wmin, __shfl_xor(wmin, off));

  int mp = max(pos[b * S_ + q0 + lane], pos[b * S_ + q0 + 64 + lane]);
#pragma unroll
  for (int off = 1; off < 64; off <<= 1) mp = max(mp, __shfl_xor(mp, off));
  const int nt = min(S_ / KVBLK, (mp >> 6) + 1);

  const int t0 = chunk * CHTILES;
  const int t1 = min(nt, t0 + CHTILES);
  if (t0 >= t1) return;                 // uniform per block
  const bool needs_merge = (nt > CHTILES);

  bf16x8 qf[4];
#pragma unroll
  for (int c = 0; c < 4; c++)
    qf[c] = *(const bf16x8*)(Qb + (size_t)qrow * HD_ + c * 16 + hi * 8);

  const int r0 = t >> 3, c0 = t & 7;
  const int r1 = (t + 256) >> 3, c1 = t & 7;
  const bf16_t* KgA = Kb + (size_t)r0 * HD_ + ((c0 ^ (r0 & 7)) * 8);
  const bf16_t* KgB = Kb + (size_t)r1 * HD_ + ((c1 ^ (r1 & 7)) * 8);
  const bf16_t* VgA = Vb + (size_t)r0 * S_ + ((c0 ^ (r0 & 7)) * 8);
  const bf16_t* VgB = Vb + (size_t)r1 * S_ + ((c1 ^ (r1 & 7)) * 8);
  const int ldsA = t * 8, ldsB = (t + 256) * 8;

  f32x16 oT[2];
#pragma unroll
  for (int dt = 0; dt < 2; dt++)
#pragma unroll
    for (int r = 0; r < 16; r++) oT[dt][r] = 0.f;
  float m_run = NINF, l_run = 0.f;

  {
    const int kn = t0 * KVBLK;
    gload_lds16(KgA + (size_t)kn * HD_, Ks[0] + ldsA);
    gload_lds16(KgB + (size_t)kn * HD_, Ks[0] + ldsB);
    gload_lds16(VgA + kn, Vs[0] + ldsA);
    gload_lds16(VgB + kn, Vs[0] + ldsB);
  }
  __syncthreads();

  for (int kt = t0; kt < t1; ++kt) {
    const int k0 = kt * KVBLK;
    const int cur = kt & 1;
    if (kt + 1 < t1) {
      const int kn = (kt + 1) * KVBLK;
      gload_lds16(KgA + (size_t)kn * HD_, Ks[cur ^ 1] + ldsA);
      gload_lds16(KgB + (size_t)kn * HD_, Ks[cur ^ 1] + ldsB);
      gload_lds16(VgA + kn, Vs[cur ^ 1] + ldsA);
      gload_lds16(VgB + kn, Vs[cur ^ 1] + ldsB);
    }
    const bf16_t* Kc = Ks[cur];
    const bf16_t* Vc = Vs[cur];

    f32x16 s0, s1;
#pragma unroll
    for (int r = 0; r < 16; r++) { s0[r] = 0.f; s1[r] = 0.f; }
    __builtin_amdgcn_s_setprio(1);
#pragma unroll
    for (int c = 0; c < 4; c++) {
      const int c2 = c * 2 + hi;
      const int kr0 = l31;
      const int kr1 = 32 + l31;
      bf16x8 kf0 = *(const bf16x8*)(Kc + kr0 * 64 + ((c2 ^ (kr0 & 7)) * 8));
      bf16x8 kf1 = *(const bf16x8*)(Kc + kr1 * 64 + ((c2 ^ (kr1 & 7)) * 8));
      s0 = __builtin_amdgcn_mfma_f32_32x32x16_bf16(kf0, qf[c], s0, 0, 0, 0);
      s1 = __builtin_amdgcn_mfma_f32_32x32x16_bf16(kf1, qf[c], s1, 0, 0, 0);
    }
    __builtin_amdgcn_s_setprio(0);

    float p0[16], p1[16];
    if (k0 + 63 > wmin) {
#pragma unroll
      for (int r = 0; r < 16; r++) {
        int koff = (r & 3) + 8 * (r >> 2) + 4 * hi;
        p0[r] = (k0 + koff <= prow) ? s0[r] : NINF;
        p1[r] = (k0 + 32 + koff <= prow) ? s1[r] : NINF;
      }
    } else {
#pragma unroll
      for (int r = 0; r < 16; r++) { p0[r] = s0[r]; p1[r] = s1[r]; }
    }

    float tm = NINF;
#pragma unroll
    for (int r = 0; r < 16; r++) tm = fmaxf(tm, fmaxf(p0[r], p1[r]));
    tm = fmaxf(tm, __shfl_xor(tm, 32));
    if (__any(tm > m_run + 8.0f)) {
      float mn = fmaxf(fmaxf(m_run, tm), -1e30f);
      float scale = exp2f((m_run - mn) * L2E);
      l_run *= scale;
#pragma unroll
      for (int dt = 0; dt < 2; dt++)
#pragma unroll
        for (int r = 0; r < 16; r++) oT[dt][r] *= scale;
      m_run = mn;
    }
    const float mnl = (m_run == NINF) ? 3.0e38f : m_run * L2E;
    float rs = 0.f;
#pragma unroll
    for (int r = 0; r < 16; r++) {
      p0[r] = exp2f(p0[r] * L2E - mnl);
      p1[r] = exp2f(p1[r] * L2E - mnl);
      rs += p0[r] + p1[r];
    }
    rs += __shfl_xor(rs, 32);
    l_run += rs;

#pragma unroll
    for (int kc = 0; kc < 4; kc++) {
      const float* P = (kc < 2) ? p0 : p1;
      const int rb = (kc & 1) * 8;
      uint32_t xa0 = packbf(P[rb + 0], P[rb + 1]);
      uint32_t xa1 = packbf(P[rb + 2], P[rb + 3]);
      uint32_t xb0 = packbf(P[rb + 4], P[rb + 5]);
      uint32_t xb1 = packbf(P[rb + 6], P[rb + 7]);
      uint32_t sa0 = (uint32_t)__shfl_xor((int)xa0, 32);
      uint32_t sa1 = (uint32_t)__shfl_xor((int)xa1, 32);
      uint32_t sb0 = (uint32_t)__shfl_xor((int)xb0, 32);
      uint32_t sb1 = (uint32_t)__shfl_xor((int)xb1, 32);
      union { uint32_t u[4]; bf16x8 v; } pf;
      pf.u[0] = hi ? sb0 : xa0;
      pf.u[1] = hi ? sb1 : xa1;
      pf.u[2] = hi ? xb0 : sa0;
      pf.u[3] = hi ? xb1 : sa1;
      __builtin_amdgcn_s_setprio(1);
#pragma unroll
      for (int dt = 0; dt < 2; dt++) {
        const int vr = dt * 32 + l31;
        const int c2 = kc * 2 + hi;
        bf16x8 vf = *(const bf16x8*)(Vc + vr * 64 + ((c2 ^ (vr & 7)) * 8));
        oT[dt] = __builtin_amdgcn_mfma_f32_32x32x16_bf16(vf, pf.v, oT[dt], 0, 0, 0);
      }
      __builtin_amdgcn_s_setprio(0);
    }

    __syncthreads();
  }

  const float rl = needs_merge ? 1.0f : ((l_run > 0.f) ? 1.0f / l_run : 0.f);
  bf16_t* Ot = (bf16_t*)Ks + wv * 2048;
#pragma unroll
  for (int dt = 0; dt < 2; dt++)
#pragma unroll
    for (int r = 0; r < 16; r++) {
      int chunkq = dt * 4 + (r >> 2);
      int el = (r & 3) + 4 * hi;
      Ot[l31 * 64 + ((chunkq ^ (l31 & 7)) * 8) + el] = (__bf16)(oT[dt][r] * rl);
    }
  __syncthreads();
  if (needs_merge) {
    bf16_t* dst = ((chunk < 3) ? (Op0 + (size_t)chunk * CHELEMS) : Op3)
                + ((size_t)(bh * 16 + qblk) * 128) * 64;
#pragma unroll
    for (int it = 0; it < 4; it++) {
      int qr2 = (lane >> 3) + it * 8;
      int cc = lane & 7;
      bf16x8 vv = *(const bf16x8*)(Ot + qr2 * 64 + ((cc ^ (qr2 & 7)) * 8));
      *(bf16x8*)(&dst[(size_t)(wv * 32 + qr2) * 64 + cc * 8]) = vv;
    }
    if (hi == 0) {
      size_t sidx = ((size_t)(chunk * 32 + bh) * 16 + qblk) * 128 + wv * 32 + l31;
      Mst[sidx] = m_run;
      Lst[sidx] = l_run;
    }
  } else {
#pragma unroll
    for (int it = 0; it < 4; it++) {
      int qr2 = (lane >> 3) + it * 8;
      int cc = lane & 7;
      bf16x8 vv = *(const bf16x8*)(Ot + qr2 * 64 + ((cc ^ (qr2 & 7)) * 8));
      *(bf16x8*)(&O[(size_t)(b * S_ + q0 + wv * 32 + qr2) * D_ + h * 64 + cc * 8]) = vv;
    }
  }
}

// ---------------- split-KV merge over nch = ceil(nt/8) chunks ----------------
__global__ __launch_bounds__(256) void attn_merge_kernel(const bf16_t* __restrict__ Op0,
                                                         const bf16_t* __restrict__ Op3,
                                                         const float* __restrict__ Mst,
                                                         const float* __restrict__ Lst,
                                                         const int* __restrict__ pos,
                                                         bf16_t* __restrict__ O) {
  __shared__ int wmax_s[4];
  const int t = threadIdx.x;
  const int bid = blockIdx.x;
  const int bh = (bid & 7) * 4 + ((bid >> 3) & 3);
  const int qblk = 15 - (bid >> 5);
  const int b = bh >> 4, h = bh & 15;
  const int q0 = qblk * 128;

  int p = pos[b * S_ + q0 + (t & 127)];
#pragma unroll
  for (int off = 1; off < 64; off <<= 1) p = max(p, __shfl_xor(p, off));
  if ((t & 63) == 0) wmax_s[t >> 6] = p;
  __syncthreads();
  int mp = max(max(wmax_s[0], wmax_s[1]), max(wmax_s[2], wmax_s[3]));
  const int nt = min(S_ / KVBLK, (mp >> 6) + 1);
  const int nch = (nt + CHTILES - 1) / CHTILES;
  if (nch <= 1) return;   // attn wrote final O directly

  const int r = t >> 1, dh = (t & 1) * 32;
  const size_t rowoff = ((size_t)(bh * 16 + qblk) * 128 + r) * 64 + dh;

  float mc[4], lc[4];
  float m = -1e30f;
  for (int c = 0; c < nch; c++) {
    size_t sidx = ((size_t)(c * 32 + bh) * 16 + qblk) * 128 + r;
    mc[c] = Mst[sidx];
    lc[c] = Lst[sidx];
    m = fmaxf(m, mc[c]);
  }
  float accv[32];
#pragma unroll
  for (int j = 0; j < 32; j++) accv[j] = 0.f;
  float lt = 0.f;
  for (int c = 0; c < nch; c++) {
    float wgt = exp2f((mc[c] - m) * L2E);
    lt += lc[c] * wgt;
    const bf16_t* pc = ((c < 3) ? (Op0 + (size_t)c * CHELEMS) : Op3) + rowoff;
#pragma unroll
    for (int cc4 = 0; cc4 < 4; cc4++) {
      bf16x8 v = *(const bf16x8*)(pc + cc4 * 8);
#pragma unroll
      for (int j = 0; j < 8; j++) accv[cc4 * 8 + j] += wgt * (float)v[j];
    }
  }
  const float rl = (lt > 0.f) ? 1.0f / lt : 0.f;
  bf16_t* dst = O + (size_t)(b * S_ + q0 + r) * D_ + h * 64 + dh;
#pragma unroll
  for (int cc4 = 0; cc4 < 4; cc4++) {
    bf16x8 o;
#pragma unroll
    for (int j = 0; j < 8; j++) o[j] = (__bf16)(accv[cc4 * 8 + j] * rl);
    *(bf16x8*)(dst + cc4 * 8) = o;
  }
}

extern "C" void kernel_launch(void* const* d_in, const int* in_sizes, int n_in,
                              void* d_out, int out_size, void* d_ws, size_t ws_size,
                              hipStream_t stream) {
  const float* inputs = (const float*)d_in[0];
  const int* positions = (const int*)d_in[1];
  const float* W_in = (const float*)d_in[2];
  const float* W_out = (const float*)d_in[3];
  float* out = (float*)d_out;

  bf16_t* X_bf = (bf16_t*)d_ws;                       // 4096*1024 (dead after qkv-gemm)
  bf16_t* Win_bf = X_bf + (size_t)4096 * 1024;        // 3072*1024 (dead after qkv-gemm)
  bf16_t* Wout_bf = Win_bf + (size_t)3072 * 1024;     // live until gemm2
  bf16_t* scratch = Wout_bf + (size_t)1024 * 1024;    // 4096*3072 (dead: qkv never stored)
  bf16_t* Qb = scratch + (size_t)4096 * 3072;
  bf16_t* Kb = Qb + (size_t)B_ * H_ * S_ * HD_;
  bf16_t* Vtb = Kb + (size_t)B_ * H_ * S_ * HD_;
  bf16_t* Ob = Vtb + (size_t)B_ * H_ * S_ * HD_;

  // split-KV x4 partials: chunks 0-2 fill scratch exactly (3*CHELEMS = 4096*3072);
  // chunk 3 fills X_bf exactly (CHELEMS = 4096*1024); stats in Win_bf (2MB of 6.3MB).
  bf16_t* Op0 = scratch;
  bf16_t* Op3 = X_bf;
  float* Mst = (float*)Win_bf;
  float* Lst = Mst + (size_t)4 * 32 * 16 * 128;

  cast3_bf16_kernel<<<dim3(2048), dim3(256), 0, stream>>>(
      inputs, X_bf, (4096 * 1024) / 4,
      W_in, Win_bf, (3072 * 1024) / 4,
      W_out, Wout_bf, (1024 * 1024) / 4);

  gemm_qkv_rope<<<dim3(16, 12), dim3(512), 0, stream>>>(X_bf, Win_bf, positions, Qb, Kb, Vtb);

  attn_kernel<<<dim3(2048), dim3(256), 0, stream>>>(Qb, Kb, Vtb, positions, Ob, Op0, Op3, Mst, Lst);
  attn_merge_kernel<<<dim3(512), dim3(256), 0, stream>>>(Op0, Op3, Mst, Lst, positions, Ob);

  gemm_bt<float><<<dim3(32, 8), dim3(256), 0, stream>>>(Ob, Wout_bf, out, 4096, 1024, 1024);
}

// Round 16
// 136.928 us; speedup vs baseline: 1.3166x; 1.0325x over previous
//
#include <hip/hip_runtime.h>
#include <stdint.h>
#include <math.h>

#define B_ 2
#define S_ 2048
#define D_ 1024
#define H_ 16
#define HD_ 64
#define KVBLK 64
#define CHTILES 8                 // kv tiles per split chunk
#define CHELEMS ((size_t)32 * 16 * 128 * 64)   // bf16 elems per chunk partial

typedef __bf16 bf16_t;
typedef __bf16 bf16x4 __attribute__((ext_vector_type(4)));
typedef __bf16 bf16x8 __attribute__((ext_vector_type(8)));
typedef float f32x4 __attribute__((ext_vector_type(4)));
typedef float f32x16 __attribute__((ext_vector_type(16)));
typedef float float4v __attribute__((ext_vector_type(4)));

#define L2E 1.4426950408889634f
#define NINF (-__builtin_inff())

__device__ __forceinline__ void gload_lds16(const bf16_t* g, bf16_t* l) {
  __builtin_amdgcn_global_load_lds((const __attribute__((address_space(1))) void*)g,
                                   (__attribute__((address_space(3))) void*)l, 16, 0, 0);
}

__device__ __forceinline__ uint32_t packbf(float a, float b) {
  union { __bf16 h[2]; uint32_t u; } cvt;
  cvt.h[0] = (__bf16)a; cvt.h[1] = (__bf16)b;
  return cvt.u;
}

// ---------------- fused cast f32 -> bf16 for all three inputs (vector x4) ----------------
__global__ void cast3_bf16_kernel(const float* __restrict__ s0, bf16_t* __restrict__ d0, int n0,
                                  const float* __restrict__ s1, bf16_t* __restrict__ d1, int n1,
                                  const float* __restrict__ s2, bf16_t* __restrict__ d2, int n2) {
  int i = blockIdx.x * blockDim.x + threadIdx.x;
  int stride = gridDim.x * blockDim.x;
  int tot = n0 + n1 + n2;
  for (; i < tot; i += stride) {
    const float* s; bf16_t* d; int j = i;
    if (j < n0) { s = s0; d = d0; }
    else if ((j -= n0) < n1) { s = s1; d = d1; }
    else { j -= n1; s = s2; d = d2; }
    float4v f = *(const float4v*)(s + (size_t)j * 4);
    bf16x4 o;
    o[0] = (__bf16)f[0]; o[1] = (__bf16)f[1]; o[2] = (__bf16)f[2]; o[3] = (__bf16)f[3];
    *(bf16x4*)(d + (size_t)j * 4) = o;
  }
}

// ------- gemm2: 128x64-tile GEMM (2 blocks/CU vs the 128^2 kernel's 1/CU at N=1024) -------
// C[m][n] = sum_k A[m][k]*B[n][k]; grid (M/128, N/64), 256 thr = 2x2 waves, wave-tile 64x32.
template <typename OutT>
__global__ __launch_bounds__(256) void gemm_bt64(const bf16_t* __restrict__ A,
                                                 const bf16_t* __restrict__ Bm,
                                                 OutT* __restrict__ C,
                                                 int M, int N, int K) {
  __shared__ bf16_t As[128 * 32];   // 8KB
  __shared__ bf16_t Bs[64 * 32];    // 4KB
  const int t = threadIdx.x;
  const int lane = t & 63, wave = t >> 6;
  const int wr = wave >> 1, wc = wave & 1;
  const int qr = lane & 15, g = lane >> 4;
  const int bm = blockIdx.x, bn = blockIdx.y;

  f32x4 acc[4][2];
#pragma unroll
  for (int m = 0; m < 4; m++)
#pragma unroll
    for (int n = 0; n < 2; n++) acc[m][n] = (f32x4){0.f, 0.f, 0.f, 0.f};

  const bf16_t* Abase = A + (size_t)(bm * 128) * K;
  const bf16_t* Bbase = Bm + (size_t)(bn * 64) * K;
  const int srow = t >> 2;            // 0..63
  const int scol = (t & 3) * 8;

  for (int kk = 0; kk < K; kk += 32) {
    gload_lds16(Abase + (size_t)srow * K + kk + scol,        As + t * 8);
    gload_lds16(Abase + (size_t)(srow + 64) * K + kk + scol, As + 2048 + t * 8);
    gload_lds16(Bbase + (size_t)srow * K + kk + scol,        Bs + t * 8);
    __syncthreads();
    bf16x8 a[4], b[2];
#pragma unroll
    for (int m = 0; m < 4; m++)
      a[m] = *(const bf16x8*)(As + (wr * 64 + m * 16 + qr) * 32 + g * 8);
#pragma unroll
    for (int n = 0; n < 2; n++)
      b[n] = *(const bf16x8*)(Bs + (wc * 32 + n * 16 + qr) * 32 + g * 8);
#pragma unroll
    for (int m = 0; m < 4; m++)
#pragma unroll
      for (int n = 0; n < 2; n++)
        acc[m][n] = __builtin_amdgcn_mfma_f32_16x16x32_bf16(a[m], b[n], acc[m][n], 0, 0, 0);
    __syncthreads();
  }

#pragma unroll
  for (int m = 0; m < 4; m++) {
    int row0 = bm * 128 + wr * 64 + m * 16 + g * 4;
#pragma unroll
    for (int n = 0; n < 2; n++) {
      int col = bn * 64 + wc * 32 + n * 16 + qr;
#pragma unroll
      for (int r = 0; r < 4; r++)
        C[(size_t)(row0 + r) * N + col] = (OutT)acc[m][n][r];
    }
  }
}

// ---- fused QKV GEMM + RoPE + q-scale + V-transpose (R14-proven; native __sinf/__cosf) ----
__global__ __launch_bounds__(512, 1) void gemm_qkv_rope(const bf16_t* __restrict__ A,
                                                        const bf16_t* __restrict__ Bm,
                                                        const int* __restrict__ pos,
                                                        bf16_t* __restrict__ Qd,
                                                        bf16_t* __restrict__ Kd,
                                                        bf16_t* __restrict__ Vtd) {
  const int K = D_;
  const int NT = K >> 6;
  __shared__ bf16_t As[2][256 * 64];
  __shared__ bf16_t Bs[2][256 * 64];
  const int t = threadIdx.x;
  const int lane = t & 63, wid = t >> 6;
  const int qr = lane & 15, g = lane >> 4;
  const int wm = wid >> 2, wn = wid & 3;
  const int bm = blockIdx.x, bn = blockIdx.y;

  const bf16_t* Ab = A + (size_t)(bm * 256) * K;
  const bf16_t* Bb = Bm + (size_t)(bn * 256) * K;

  const bf16_t* srcA[4];
  const bf16_t* srcB[4];
  int ldsOff[4];
#pragma unroll
  for (int i = 0; i < 4; i++) {
    int e = t + 512 * i;
    int row = e >> 3, cs = e & 7;
    int gcol = (cs ^ (row & 7)) * 8;
    srcA[i] = Ab + (size_t)row * K + gcol;
    srcB[i] = Bb + (size_t)row * K + gcol;
    ldsOff[i] = e * 8;
  }

  f32x4 acc[8][4];
#pragma unroll
  for (int m = 0; m < 8; m++)
#pragma unroll
    for (int n = 0; n < 4; n++) acc[m][n] = (f32x4){0.f, 0.f, 0.f, 0.f};

#define RD(buf_, r_, k_) (*(const bf16x8*)((buf_) + (r_) * 64 + ((((k_) * 4 + g) ^ ((r_) & 7)) * 8)))

#pragma unroll
  for (int i = 0; i < 4; i++) gload_lds16(srcA[i], As[0] + ldsOff[i]);
#pragma unroll
  for (int i = 0; i < 4; i++) gload_lds16(srcB[i], Bs[0] + ldsOff[i]);
#pragma unroll
  for (int i = 0; i < 4; i++) gload_lds16(srcA[i] + 64, As[1] + ldsOff[i]);
#pragma unroll
  for (int i = 0; i < 4; i++) gload_lds16(srcB[i] + 64, Bs[1] + ldsOff[i]);

  for (int T = 0; T < NT; ++T) {
    bf16_t* A_c = As[T & 1];
    bf16_t* B_c = Bs[T & 1];
    if (T + 1 < NT) asm volatile("s_waitcnt vmcnt(8)" ::: "memory");
    else            asm volatile("s_waitcnt vmcnt(0)" ::: "memory");
    __builtin_amdgcn_sched_barrier(0);
    __builtin_amdgcn_s_barrier();

    const bool st = (T + 2 < NT);
    const int kt2 = (T + 2) * 64;

    bf16x8 alo[4][2], ahi[4][2], bfr[4][2];

    // ---- ph0 ----
#pragma unroll
    for (int m = 0; m < 4; m++) {
      int r = wm * 128 + m * 16 + qr;
      alo[m][0] = RD(A_c, r, 0); alo[m][1] = RD(A_c, r, 1);
    }
#pragma unroll
    for (int n = 0; n < 2; n++) {
      int r = wn * 64 + n * 16 + qr;
      bfr[n][0] = RD(B_c, r, 0); bfr[n][1] = RD(B_c, r, 1);
    }
    __builtin_amdgcn_s_barrier();
    __builtin_amdgcn_s_setprio(1);
#pragma unroll
    for (int m = 0; m < 4; m++)
#pragma unroll
      for (int n = 0; n < 2; n++)
#pragma unroll
        for (int k = 0; k < 2; k++)
          acc[m][n] = __builtin_amdgcn_mfma_f32_16x16x32_bf16(alo[m][k], bfr[n][k], acc[m][n], 0, 0, 0);
    __builtin_amdgcn_s_setprio(0);
    __builtin_amdgcn_s_barrier();

    // ---- ph1 ----
#pragma unroll
    for (int n = 2; n < 4; n++) {
      int r = wn * 64 + n * 16 + qr;
      bfr[n][0] = RD(B_c, r, 0); bfr[n][1] = RD(B_c, r, 1);
    }
    if (st) {
      gload_lds16(srcA[0] + kt2, A_c + ldsOff[0]);
      gload_lds16(srcA[2] + kt2, A_c + ldsOff[2]);
    }
    __builtin_amdgcn_s_barrier();
    __builtin_amdgcn_s_setprio(1);
#pragma unroll
    for (int m = 0; m < 4; m++)
#pragma unroll
      for (int n = 2; n < 4; n++)
#pragma unroll
        for (int k = 0; k < 2; k++)
          acc[m][n] = __builtin_amdgcn_mfma_f32_16x16x32_bf16(alo[m][k], bfr[n][k], acc[m][n], 0, 0, 0);
    __builtin_amdgcn_s_setprio(0);
    __builtin_amdgcn_s_barrier();

    // ---- ph2 ----
#pragma unroll
    for (int m = 0; m < 4; m++) {
      int r = wm * 128 + (m + 4) * 16 + qr;
      ahi[m][0] = RD(A_c, r, 0); ahi[m][1] = RD(A_c, r, 1);
    }
    if (st) {
      gload_lds16(srcB[0] + kt2, B_c + ldsOff[0]);
      gload_lds16(srcB[1] + kt2, B_c + ldsOff[1]);
      gload_lds16(srcB[2] + kt2, B_c + ldsOff[2]);
      gload_lds16(srcB[3] + kt2, B_c + ldsOff[3]);
    }
    __builtin_amdgcn_s_barrier();
    __builtin_amdgcn_s_setprio(1);
#pragma unroll
    for (int m = 0; m < 4; m++)
#pragma unroll
      for (int n = 0; n < 2; n++)
#pragma unroll
        for (int k = 0; k < 2; k++)
          acc[m + 4][n] = __builtin_amdgcn_mfma_f32_16x16x32_bf16(ahi[m][k], bfr[n][k], acc[m + 4][n], 0, 0, 0);
    __builtin_amdgcn_s_setprio(0);
    __builtin_amdgcn_s_barrier();

    // ---- ph3 ----
    if (st) {
      gload_lds16(srcA[1] + kt2, A_c + ldsOff[1]);
      gload_lds16(srcA[3] + kt2, A_c + ldsOff[3]);
    }
    __builtin_amdgcn_s_barrier();
    __builtin_amdgcn_s_setprio(1);
#pragma unroll
    for (int m = 0; m < 4; m++)
#pragma unroll
      for (int n = 2; n < 4; n++)
#pragma unroll
        for (int k = 0; k < 2; k++)
          acc[m + 4][n] = __builtin_amdgcn_mfma_f32_16x16x32_bf16(ahi[m][k], bfr[n][k], acc[m + 4][n], 0, 0, 0);
    __builtin_amdgcn_s_setprio(0);
    __builtin_amdgcn_s_barrier();
  }
#undef RD

  // ---- fused epilogue via per-wave LDS staging (coalesced stores) ----
  __syncthreads();
  bf16_t* myLds = (wid < 4) ? ((bf16_t*)As + wid * 8192) : ((bf16_t*)Bs + (wid - 4) * 8192);

  const int w = bn * 4 + wn;
  const int typ = w % 3;
  const int head = w / 3;
  const int rowbase = bm * 256 + wm * 128;
  const int b = rowbase >> 11;
  const int s0w = rowbase & (S_ - 1);

  if (typ == 2) {
#pragma unroll
    for (int m = 0; m < 8; m++) {
      int sl0 = m * 16 + g * 4;
#pragma unroll
      for (int n = 0; n < 4; n++) {
        int d = n * 16 + qr;
#pragma unroll
        for (int rr = 0; rr < 4; rr++) {
          int sl = sl0 + rr;
          myLds[d * 128 + (((sl >> 3) ^ (d & 15)) * 8) + (sl & 7)] = (__bf16)acc[m][n][rr];
        }
      }
    }
    bf16_t* dstv = Vtd + (size_t)(b * H_ + head) * HD_ * S_ + s0w;
#pragma unroll
    for (int it = 0; it < 16; it++) {
      int d = (lane >> 4) + it * 4;
      int sc = lane & 15;
      bf16x8 v = *(const bf16x8*)(myLds + d * 128 + ((sc ^ (d & 15)) * 8));
      *(bf16x8*)(dstv + (size_t)d * S_ + sc * 8) = v;
    }
  } else {
    const float qs = (typ == 0) ? 0.125f : 1.0f;
    const float l2r = 13.287712379549449f / 32.0f;
    float inv[2];
    inv[0] = exp2f(-(float)qr * l2r);
    inv[1] = exp2f(-(float)(qr + 16) * l2r);
#pragma unroll
    for (int m = 0; m < 8; m++) {
      int r0 = m * 16 + g * 4;
#pragma unroll
      for (int rr = 0; rr < 4; rr++) {
        int r = r0 + rr;
        float p = (float)pos[rowbase + r];
#pragma unroll
        for (int n = 0; n < 2; n++) {
          float ang = p * inv[n];
          float sn = __sinf(ang);
          float cs = __cosf(ang);
          float x1 = acc[m][n][rr], x2 = acc[m][n + 2][rr];
          float o1 = (x1 * cs - x2 * sn) * qs;
          float o2 = (x2 * cs + x1 * sn) * qs;
          int d1 = n * 16 + qr, d2 = d1 + 32;
          myLds[r * 64 + (((d1 >> 3) ^ (r & 7)) * 8) + (d1 & 7)] = (__bf16)o1;
          myLds[r * 64 + (((d2 >> 3) ^ (r & 7)) * 8) + (d2 & 7)] = (__bf16)o2;
        }
      }
    }
    bf16_t* dstb = ((typ == 0) ? Qd : Kd) + (size_t)(b * H_ + head) * S_ * HD_ + (size_t)s0w * HD_;
#pragma unroll
    for (int it = 0; it < 16; it++) {
      int r = (lane >> 3) + it * 8;
      int cc = lane & 7;
      bf16x8 v = *(const bf16x8*)(myLds + r * 64 + ((cc ^ (r & 7)) * 8));
      *(bf16x8*)(dstb + (size_t)r * HD_ + cc * 8) = v;
    }
  }
}

// ---------------- flash attention: split-KV x4 chunks + XCD-resident KV mapping ----------------
__global__ __launch_bounds__(256) void attn_kernel(const bf16_t* __restrict__ Q,
                                                   const bf16_t* __restrict__ K,
                                                   const bf16_t* __restrict__ Vt,
                                                   const int* __restrict__ pos,
                                                   bf16_t* __restrict__ O,
                                                   bf16_t* __restrict__ Op0,
                                                   bf16_t* __restrict__ Op3,
                                                   float* __restrict__ Mst,
                                                   float* __restrict__ Lst) {
  __shared__ bf16_t Ks[2][64 * 64];
  __shared__ bf16_t Vs[2][64 * 64];

  const int t = threadIdx.x;
  const int lane = t & 63, wv = t >> 6;
  const int l31 = lane & 31, hi = lane >> 5;

  const int bid = blockIdx.x;
  const int bh = (bid & 7) * 4 + ((bid >> 3) & 3);
  const int v6 = bid >> 5;
  const int qblk = 15 - (v6 >> 2);
  const int chunk = v6 & 3;
  const int b = bh >> 4, h = bh & 15;
  const int q0 = qblk * 128;

  const bf16_t* Qb = Q + (size_t)bh * (S_ * HD_);
  const bf16_t* Kb = K + (size_t)bh * (S_ * HD_);
  const bf16_t* Vb = Vt + (size_t)bh * (HD_ * S_);

  const int qrow = q0 + wv * 32 + l31;

  const int prow = pos[b * S_ + qrow];
  int wmin = prow;
#pragma unroll
  for (int off = 1; off < 32; off <<= 1) wmin = min(wmin, __shfl_xor(wmin, off));

  int mp = max(pos[b * S_ + q0 + lane], pos[b * S_ + q0 + 64 + lane]);
#pragma unroll
  for (int off = 1; off < 64; off <<= 1) mp = max(mp, __shfl_xor(mp, off));
  const int nt = min(S_ / KVBLK, (mp >> 6) + 1);

  const int t0 = chunk * CHTILES;
  const int t1 = min(nt, t0 + CHTILES);
  if (t0 >= t1) return;
  const bool needs_merge = (nt > CHTILES);

  bf16x8 qf[4];
#pragma unroll
  for (int c = 0; c < 4; c++)
    qf[c] = *(const bf16x8*)(Qb + (size_t)qrow * HD_ + c * 16 + hi * 8);

  const int r0 = t >> 3, c0 = t & 7;
  const int r1 = (t + 256) >> 3, c1 = t & 7;
  const bf16_t* KgA = Kb + (size_t)r0 * HD_ + ((c0 ^ (r0 & 7)) * 8);
  const bf16_t* KgB = Kb + (size_t)r1 * HD_ + ((c1 ^ (r1 & 7)) * 8);
  const bf16_t* VgA = Vb + (size_t)r0 * S_ + ((c0 ^ (r0 & 7)) * 8);
  const bf16_t* VgB = Vb + (size_t)r1 * S_ + ((c1 ^ (r1 & 7)) * 8);
  const int ldsA = t * 8, ldsB = (t + 256) * 8;

  f32x16 oT[2];
#pragma unroll
  for (int dt = 0; dt < 2; dt++)
#pragma unroll
    for (int r = 0; r < 16; r++) oT[dt][r] = 0.f;
  float m_run = NINF, l_run = 0.f;

  {
    const int kn = t0 * KVBLK;
    gload_lds16(KgA + (size_t)kn * HD_, Ks[0] + ldsA);
    gload_lds16(KgB + (size_t)kn * HD_, Ks[0] + ldsB);
    gload_lds16(VgA + kn, Vs[0] + ldsA);
    gload_lds16(VgB + kn, Vs[0] + ldsB);
  }
  __syncthreads();

  for (int kt = t0; kt < t1; ++kt) {
    const int k0 = kt * KVBLK;
    const int cur = kt & 1;
    if (kt + 1 < t1) {
      const int kn = (kt + 1) * KVBLK;
      gload_lds16(KgA + (size_t)kn * HD_, Ks[cur ^ 1] + ldsA);
      gload_lds16(KgB + (size_t)kn * HD_, Ks[cur ^ 1] + ldsB);
      gload_lds16(VgA + kn, Vs[cur ^ 1] + ldsA);
      gload_lds16(VgB + kn, Vs[cur ^ 1] + ldsB);
    }
    const bf16_t* Kc = Ks[cur];
    const bf16_t* Vc = Vs[cur];

    f32x16 s0, s1;
#pragma unroll
    for (int r = 0; r < 16; r++) { s0[r] = 0.f; s1[r] = 0.f; }
    __builtin_amdgcn_s_setprio(1);
#pragma unroll
    for (int c = 0; c < 4; c++) {
      const int c2 = c * 2 + hi;
      const int kr0 = l31;
      const int kr1 = 32 + l31;
      bf16x8 kf0 = *(const bf16x8*)(Kc + kr0 * 64 + ((c2 ^ (kr0 & 7)) * 8));
      bf16x8 kf1 = *(const bf16x8*)(Kc + kr1 * 64 + ((c2 ^ (kr1 & 7)) * 8));
      s0 = __builtin_amdgcn_mfma_f32_32x32x16_bf16(kf0, qf[c], s0, 0, 0, 0);
      s1 = __builtin_amdgcn_mfma_f32_32x32x16_bf16(kf1, qf[c], s1, 0, 0, 0);
    }
    __builtin_amdgcn_s_setprio(0);

    float p0[16], p1[16];
    if (k0 + 63 > wmin) {
#pragma unroll
      for (int r = 0; r < 16; r++) {
        int koff = (r & 3) + 8 * (r >> 2) + 4 * hi;
        p0[r] = (k0 + koff <= prow) ? s0[r] : NINF;
        p1[r] = (k0 + 32 + koff <= prow) ? s1[r] : NINF;
      }
    } else {
#pragma unroll
      for (int r = 0; r < 16; r++) { p0[r] = s0[r]; p1[r] = s1[r]; }
    }

    float tm = NINF;
#pragma unroll
    for (int r = 0; r < 16; r++) tm = fmaxf(tm, fmaxf(p0[r], p1[r]));
    tm = fmaxf(tm, __shfl_xor(tm, 32));
    if (__any(tm > m_run + 8.0f)) {
      float mn = fmaxf(fmaxf(m_run, tm), -1e30f);
      float scale = exp2f((m_run - mn) * L2E);
      l_run *= scale;
#pragma unroll
      for (int dt = 0; dt < 2; dt++)
#pragma unroll
        for (int r = 0; r < 16; r++) oT[dt][r] *= scale;
      m_run = mn;
    }
    const float mnl = (m_run == NINF) ? 3.0e38f : m_run * L2E;
    float rs = 0.f;
#pragma unroll
    for (int r = 0; r < 16; r++) {
      p0[r] = exp2f(p0[r] * L2E - mnl);
      p1[r] = exp2f(p1[r] * L2E - mnl);
      rs += p0[r] + p1[r];
    }
    rs += __shfl_xor(rs, 32);
    l_run += rs;

#pragma unroll
    for (int kc = 0; kc < 4; kc++) {
      const float* P = (kc < 2) ? p0 : p1;
      const int rb = (kc & 1) * 8;
      uint32_t xa0 = packbf(P[rb + 0], P[rb + 1]);
      uint32_t xa1 = packbf(P[rb + 2], P[rb + 3]);
      uint32_t xb0 = packbf(P[rb + 4], P[rb + 5]);
      uint32_t xb1 = packbf(P[rb + 6], P[rb + 7]);
      uint32_t sa0 = (uint32_t)__shfl_xor((int)xa0, 32);
      uint32_t sa1 = (uint32_t)__shfl_xor((int)xa1, 32);
      uint32_t sb0 = (uint32_t)__shfl_xor((int)xb0, 32);
      uint32_t sb1 = (uint32_t)__shfl_xor((int)xb1, 32);
      union { uint32_t u[4]; bf16x8 v; } pf;
      pf.u[0] = hi ? sb0 : xa0;
      pf.u[1] = hi ? sb1 : xa1;
      pf.u[2] = hi ? xb0 : sa0;
      pf.u[3] = hi ? xb1 : sa1;
      __builtin_amdgcn_s_setprio(1);
#pragma unroll
      for (int dt = 0; dt < 2; dt++) {
        const int vr = dt * 32 + l31;
        const int c2 = kc * 2 + hi;
        bf16x8 vf = *(const bf16x8*)(Vc + vr * 64 + ((c2 ^ (vr & 7)) * 8));
        oT[dt] = __builtin_amdgcn_mfma_f32_32x32x16_bf16(vf, pf.v, oT[dt], 0, 0, 0);
      }
      __builtin_amdgcn_s_setprio(0);
    }

    __syncthreads();
  }

  const float rl = needs_merge ? 1.0f : ((l_run > 0.f) ? 1.0f / l_run : 0.f);
  bf16_t* Ot = (bf16_t*)Ks + wv * 2048;
#pragma unroll
  for (int dt = 0; dt < 2; dt++)
#pragma unroll
    for (int r = 0; r < 16; r++) {
      int chunkq = dt * 4 + (r >> 2);
      int el = (r & 3) + 4 * hi;
      Ot[l31 * 64 + ((chunkq ^ (l31 & 7)) * 8) + el] = (__bf16)(oT[dt][r] * rl);
    }
  __syncthreads();
  if (needs_merge) {
    bf16_t* dst = ((chunk < 3) ? (Op0 + (size_t)chunk * CHELEMS) : Op3)
                + ((size_t)(bh * 16 + qblk) * 128) * 64;
#pragma unroll
    for (int it = 0; it < 4; it++) {
      int qr2 = (lane >> 3) + it * 8;
      int cc = lane & 7;
      bf16x8 vv = *(const bf16x8*)(Ot + qr2 * 64 + ((cc ^ (qr2 & 7)) * 8));
      *(bf16x8*)(&dst[(size_t)(wv * 32 + qr2) * 64 + cc * 8]) = vv;
    }
    if (hi == 0) {
      size_t sidx = ((size_t)(chunk * 32 + bh) * 16 + qblk) * 128 + wv * 32 + l31;
      Mst[sidx] = m_run;
      Lst[sidx] = l_run;
    }
  } else {
#pragma unroll
    for (int it = 0; it < 4; it++) {
      int qr2 = (lane >> 3) + it * 8;
      int cc = lane & 7;
      bf16x8 vv = *(const bf16x8*)(Ot + qr2 * 64 + ((cc ^ (qr2 & 7)) * 8));
      *(bf16x8*)(&O[(size_t)(b * S_ + q0 + wv * 32 + qr2) * D_ + h * 64 + cc * 8]) = vv;
    }
  }
}

// ---------------- split-KV merge over nch = ceil(nt/8) chunks ----------------
__global__ __launch_bounds__(256) void attn_merge_kernel(const bf16_t* __restrict__ Op0,
                                                         const bf16_t* __restrict__ Op3,
                                                         const float* __restrict__ Mst,
                                                         const float* __restrict__ Lst,
                                                         const int* __restrict__ pos,
                                                         bf16_t* __restrict__ O) {
  __shared__ int wmax_s[4];
  const int t = threadIdx.x;
  const int bid = blockIdx.x;
  const int bh = (bid & 7) * 4 + ((bid >> 3) & 3);
  const int qblk = 15 - (bid >> 5);
  const int b = bh >> 4, h = bh & 15;
  const int q0 = qblk * 128;

  int p = pos[b * S_ + q0 + (t & 127)];
#pragma unroll
  for (int off = 1; off < 64; off <<= 1) p = max(p, __shfl_xor(p, off));
  if ((t & 63) == 0) wmax_s[t >> 6] = p;
  __syncthreads();
  int mp = max(max(wmax_s[0], wmax_s[1]), max(wmax_s[2], wmax_s[3]));
  const int nt = min(S_ / KVBLK, (mp >> 6) + 1);
  const int nch = (nt + CHTILES - 1) / CHTILES;
  if (nch <= 1) return;

  const int r = t >> 1, dh = (t & 1) * 32;
  const size_t rowoff = ((size_t)(bh * 16 + qblk) * 128 + r) * 64 + dh;

  float mc[4], lc[4];
  float m = -1e30f;
  for (int c = 0; c < nch; c++) {
    size_t sidx = ((size_t)(c * 32 + bh) * 16 + qblk) * 128 + r;
    mc[c] = Mst[sidx];
    lc[c] = Lst[sidx];
    m = fmaxf(m, mc[c]);
  }
  float accv[32];
#pragma unroll
  for (int j = 0; j < 32; j++) accv[j] = 0.f;
  float lt = 0.f;
  for (int c = 0; c < nch; c++) {
    float wgt = exp2f((mc[c] - m) * L2E);
    lt += lc[c] * wgt;
    const bf16_t* pc = ((c < 3) ? (Op0 + (size_t)c * CHELEMS) : Op3) + rowoff;
#pragma unroll
    for (int cc4 = 0; cc4 < 4; cc4++) {
      bf16x8 v = *(const bf16x8*)(pc + cc4 * 8);
#pragma unroll
      for (int j = 0; j < 8; j++) accv[cc4 * 8 + j] += wgt * (float)v[j];
    }
  }
  const float rl = (lt > 0.f) ? 1.0f / lt : 0.f;
  bf16_t* dst = O + (size_t)(b * S_ + q0 + r) * D_ + h * 64 + dh;
#pragma unroll
  for (int cc4 = 0; cc4 < 4; cc4++) {
    bf16x8 o;
#pragma unroll
    for (int j = 0; j < 8; j++) o[j] = (__bf16)(accv[cc4 * 8 + j] * rl);
    *(bf16x8*)(dst + cc4 * 8) = o;
  }
}

extern "C" void kernel_launch(void* const* d_in, const int* in_sizes, int n_in,
                              void* d_out, int out_size, void* d_ws, size_t ws_size,
                              hipStream_t stream) {
  const float* inputs = (const float*)d_in[0];
  const int* positions = (const int*)d_in[1];
  const float* W_in = (const float*)d_in[2];
  const float* W_out = (const float*)d_in[3];
  float* out = (float*)d_out;

  bf16_t* X_bf = (bf16_t*)d_ws;                       // 4096*1024 (dead after qkv-gemm)
  bf16_t* Win_bf = X_bf + (size_t)4096 * 1024;        // 3072*1024 (dead after qkv-gemm)
  bf16_t* Wout_bf = Win_bf + (size_t)3072 * 1024;     // live until gemm2
  bf16_t* scratch = Wout_bf + (size_t)1024 * 1024;    // 4096*3072 (dead: qkv never stored)
  bf16_t* Qb = scratch + (size_t)4096 * 3072;
  bf16_t* Kb = Qb + (size_t)B_ * H_ * S_ * HD_;
  bf16_t* Vtb = Kb + (size_t)B_ * H_ * S_ * HD_;
  bf16_t* Ob = Vtb + (size_t)B_ * H_ * S_ * HD_;

  bf16_t* Op0 = scratch;
  bf16_t* Op3 = X_bf;
  float* Mst = (float*)Win_bf;
  float* Lst = Mst + (size_t)4 * 32 * 16 * 128;

  cast3_bf16_kernel<<<dim3(2048), dim3(256), 0, stream>>>(
      inputs, X_bf, (4096 * 1024) / 4,
      W_in, Win_bf, (3072 * 1024) / 4,
      W_out, Wout_bf, (1024 * 1024) / 4);

  gemm_qkv_rope<<<dim3(16, 12), dim3(512), 0, stream>>>(X_bf, Win_bf, positions, Qb, Kb, Vtb);

  attn_kernel<<<dim3(2048), dim3(256), 0, stream>>>(Qb, Kb, Vtb, positions, Ob, Op0, Op3, Mst, Lst);
  attn_merge_kernel<<<dim3(512), dim3(256), 0, stream>>>(Op0, Op3, Mst, Lst, positions, Ob);

  gemm_bt64<float><<<dim3(32, 16), dim3(256), 0, stream>>>(Ob, Wout_bf, out, 4096, 1024, 1024);
}

// Round 17
// 136.120 us; speedup vs baseline: 1.3244x; 1.0059x over previous
//
#include <hip/hip_runtime.h>
#include <stdint.h>
#include <math.h>

#define B_ 2
#define S_ 2048
#define D_ 1024
#define H_ 16
#define HD_ 64
#define KVBLK 64
#define CHTILES 8                 // kv tiles per split chunk
#define CHELEMS ((size_t)32 * 16 * 128 * 64)   // bf16 elems per chunk partial

typedef __bf16 bf16_t;
typedef __bf16 bf16x4 __attribute__((ext_vector_type(4)));
typedef __bf16 bf16x8 __attribute__((ext_vector_type(8)));
typedef float f32x4 __attribute__((ext_vector_type(4)));
typedef float f32x16 __attribute__((ext_vector_type(16)));
typedef float float4v __attribute__((ext_vector_type(4)));

#define L2E 1.4426950408889634f
#define NINF (-__builtin_inff())

__device__ __forceinline__ void gload_lds16(const bf16_t* g, bf16_t* l) {
  __builtin_amdgcn_global_load_lds((const __attribute__((address_space(1))) void*)g,
                                   (__attribute__((address_space(3))) void*)l, 16, 0, 0);
}

__device__ __forceinline__ uint32_t packbf(float a, float b) {
  union { __bf16 h[2]; uint32_t u; } cvt;
  cvt.h[0] = (__bf16)a; cvt.h[1] = (__bf16)b;
  return cvt.u;
}

// ---------------- fused cast f32 -> bf16 for all three inputs (vector x4) ----------------
__global__ void cast3_bf16_kernel(const float* __restrict__ s0, bf16_t* __restrict__ d0, int n0,
                                  const float* __restrict__ s1, bf16_t* __restrict__ d1, int n1,
                                  const float* __restrict__ s2, bf16_t* __restrict__ d2, int n2) {
  int i = blockIdx.x * blockDim.x + threadIdx.x;
  int stride = gridDim.x * blockDim.x;
  int tot = n0 + n1 + n2;
  for (; i < tot; i += stride) {
    const float* s; bf16_t* d; int j = i;
    if (j < n0) { s = s0; d = d0; }
    else if ((j -= n0) < n1) { s = s1; d = d1; }
    else { j -= n1; s = s2; d = d2; }
    float4v f = *(const float4v*)(s + (size_t)j * 4);
    bf16x4 o;
    o[0] = (__bf16)f[0]; o[1] = (__bf16)f[1]; o[2] = (__bf16)f[2]; o[3] = (__bf16)f[3];
    *(bf16x4*)(d + (size_t)j * 4) = o;
  }
}

// ------- gemm2: 128x64-tile GEMM, XCD-quadrant swizzle (per-XCD 3MB working set < 4MB L2) ----
// 1-D grid 512; hw xcd = bid&7 (m09). Quadrant (bm-group of 8) x (bn-group of 8):
// bm = ((xcd>>1)<<3)+(local&7), bn = ((xcd&1)<<3)+(local>>3), local = bid>>3. Bijective.
template <typename OutT>
__global__ __launch_bounds__(256) void gemm_bt64(const bf16_t* __restrict__ A,
                                                 const bf16_t* __restrict__ Bm,
                                                 OutT* __restrict__ C,
                                                 int M, int N, int K) {
  __shared__ bf16_t As[128 * 32];   // 8KB
  __shared__ bf16_t Bs[64 * 32];    // 4KB
  const int t = threadIdx.x;
  const int lane = t & 63, wave = t >> 6;
  const int wr = wave >> 1, wc = wave & 1;
  const int qr = lane & 15, g = lane >> 4;
  const int bid = blockIdx.x;
  const int xcd = bid & 7, local = bid >> 3;
  const int bm = ((xcd >> 1) << 3) + (local & 7);
  const int bn = ((xcd & 1) << 3) + (local >> 3);

  f32x4 acc[4][2];
#pragma unroll
  for (int m = 0; m < 4; m++)
#pragma unroll
    for (int n = 0; n < 2; n++) acc[m][n] = (f32x4){0.f, 0.f, 0.f, 0.f};

  const bf16_t* Abase = A + (size_t)(bm * 128) * K;
  const bf16_t* Bbase = Bm + (size_t)(bn * 64) * K;
  const int srow = t >> 2;            // 0..63
  const int scol = (t & 3) * 8;

  for (int kk = 0; kk < K; kk += 32) {
    gload_lds16(Abase + (size_t)srow * K + kk + scol,        As + t * 8);
    gload_lds16(Abase + (size_t)(srow + 64) * K + kk + scol, As + 2048 + t * 8);
    gload_lds16(Bbase + (size_t)srow * K + kk + scol,        Bs + t * 8);
    __syncthreads();
    bf16x8 a[4], b[2];
#pragma unroll
    for (int m = 0; m < 4; m++)
      a[m] = *(const bf16x8*)(As + (wr * 64 + m * 16 + qr) * 32 + g * 8);
#pragma unroll
    for (int n = 0; n < 2; n++)
      b[n] = *(const bf16x8*)(Bs + (wc * 32 + n * 16 + qr) * 32 + g * 8);
#pragma unroll
    for (int m = 0; m < 4; m++)
#pragma unroll
      for (int n = 0; n < 2; n++)
        acc[m][n] = __builtin_amdgcn_mfma_f32_16x16x32_bf16(a[m], b[n], acc[m][n], 0, 0, 0);
    __syncthreads();
  }

#pragma unroll
  for (int m = 0; m < 4; m++) {
    int row0 = bm * 128 + wr * 64 + m * 16 + g * 4;
#pragma unroll
    for (int n = 0; n < 2; n++) {
      int col = bn * 64 + wc * 32 + n * 16 + qr;
#pragma unroll
      for (int r = 0; r < 4; r++)
        C[(size_t)(row0 + r) * N + col] = (OutT)acc[m][n][r];
    }
  }
}

// ---- fused QKV GEMM + RoPE + q-scale + V-transpose; XCD-quadrant swizzle ----
// 1-D grid 192; xcd = bid&7; quadrant = 4 bm x 6 bn per XCD (A 2MB + B 3MB = 5MB working set
// vs 7MB for round-robin). bm = (xcd>>1)*4+(local&3), bn = (xcd&1)*6+(local>>2). Bijective.
__global__ __launch_bounds__(512, 1) void gemm_qkv_rope(const bf16_t* __restrict__ A,
                                                        const bf16_t* __restrict__ Bm,
                                                        const int* __restrict__ pos,
                                                        bf16_t* __restrict__ Qd,
                                                        bf16_t* __restrict__ Kd,
                                                        bf16_t* __restrict__ Vtd) {
  const int K = D_;
  const int NT = K >> 6;
  __shared__ bf16_t As[2][256 * 64];
  __shared__ bf16_t Bs[2][256 * 64];
  const int t = threadIdx.x;
  const int lane = t & 63, wid = t >> 6;
  const int qr = lane & 15, g = lane >> 4;
  const int wm = wid >> 2, wn = wid & 3;
  const int bid = blockIdx.x;
  const int xcd = bid & 7, local = bid >> 3;
  const int bm = (xcd >> 1) * 4 + (local & 3);
  const int bn = (xcd & 1) * 6 + (local >> 2);

  const bf16_t* Ab = A + (size_t)(bm * 256) * K;
  const bf16_t* Bb = Bm + (size_t)(bn * 256) * K;

  const bf16_t* srcA[4];
  const bf16_t* srcB[4];
  int ldsOff[4];
#pragma unroll
  for (int i = 0; i < 4; i++) {
    int e = t + 512 * i;
    int row = e >> 3, cs = e & 7;
    int gcol = (cs ^ (row & 7)) * 8;
    srcA[i] = Ab + (size_t)row * K + gcol;
    srcB[i] = Bb + (size_t)row * K + gcol;
    ldsOff[i] = e * 8;
  }

  f32x4 acc[8][4];
#pragma unroll
  for (int m = 0; m < 8; m++)
#pragma unroll
    for (int n = 0; n < 4; n++) acc[m][n] = (f32x4){0.f, 0.f, 0.f, 0.f};

#define RD(buf_, r_, k_) (*(const bf16x8*)((buf_) + (r_) * 64 + ((((k_) * 4 + g) ^ ((r_) & 7)) * 8)))

#pragma unroll
  for (int i = 0; i < 4; i++) gload_lds16(srcA[i], As[0] + ldsOff[i]);
#pragma unroll
  for (int i = 0; i < 4; i++) gload_lds16(srcB[i], Bs[0] + ldsOff[i]);
#pragma unroll
  for (int i = 0; i < 4; i++) gload_lds16(srcA[i] + 64, As[1] + ldsOff[i]);
#pragma unroll
  for (int i = 0; i < 4; i++) gload_lds16(srcB[i] + 64, Bs[1] + ldsOff[i]);

  for (int T = 0; T < NT; ++T) {
    bf16_t* A_c = As[T & 1];
    bf16_t* B_c = Bs[T & 1];
    if (T + 1 < NT) asm volatile("s_waitcnt vmcnt(8)" ::: "memory");
    else            asm volatile("s_waitcnt vmcnt(0)" ::: "memory");
    __builtin_amdgcn_sched_barrier(0);
    __builtin_amdgcn_s_barrier();

    const bool st = (T + 2 < NT);
    const int kt2 = (T + 2) * 64;

    bf16x8 alo[4][2], ahi[4][2], bfr[4][2];

    // ---- ph0 ----
#pragma unroll
    for (int m = 0; m < 4; m++) {
      int r = wm * 128 + m * 16 + qr;
      alo[m][0] = RD(A_c, r, 0); alo[m][1] = RD(A_c, r, 1);
    }
#pragma unroll
    for (int n = 0; n < 2; n++) {
      int r = wn * 64 + n * 16 + qr;
      bfr[n][0] = RD(B_c, r, 0); bfr[n][1] = RD(B_c, r, 1);
    }
    __builtin_amdgcn_s_barrier();
    __builtin_amdgcn_s_setprio(1);
#pragma unroll
    for (int m = 0; m < 4; m++)
#pragma unroll
      for (int n = 0; n < 2; n++)
#pragma unroll
        for (int k = 0; k < 2; k++)
          acc[m][n] = __builtin_amdgcn_mfma_f32_16x16x32_bf16(alo[m][k], bfr[n][k], acc[m][n], 0, 0, 0);
    __builtin_amdgcn_s_setprio(0);
    __builtin_amdgcn_s_barrier();

    // ---- ph1 ----
#pragma unroll
    for (int n = 2; n < 4; n++) {
      int r = wn * 64 + n * 16 + qr;
      bfr[n][0] = RD(B_c, r, 0); bfr[n][1] = RD(B_c, r, 1);
    }
    if (st) {
      gload_lds16(srcA[0] + kt2, A_c + ldsOff[0]);
      gload_lds16(srcA[2] + kt2, A_c + ldsOff[2]);
    }
    __builtin_amdgcn_s_barrier();
    __builtin_amdgcn_s_setprio(1);
#pragma unroll
    for (int m = 0; m < 4; m++)
#pragma unroll
      for (int n = 2; n < 4; n++)
#pragma unroll
        for (int k = 0; k < 2; k++)
          acc[m][n] = __builtin_amdgcn_mfma_f32_16x16x32_bf16(alo[m][k], bfr[n][k], acc[m][n], 0, 0, 0);
    __builtin_amdgcn_s_setprio(0);
    __builtin_amdgcn_s_barrier();

    // ---- ph2 ----
#pragma unroll
    for (int m = 0; m < 4; m++) {
      int r = wm * 128 + (m + 4) * 16 + qr;
      ahi[m][0] = RD(A_c, r, 0); ahi[m][1] = RD(A_c, r, 1);
    }
    if (st) {
      gload_lds16(srcB[0] + kt2, B_c + ldsOff[0]);
      gload_lds16(srcB[1] + kt2, B_c + ldsOff[1]);
      gload_lds16(srcB[2] + kt2, B_c + ldsOff[2]);
      gload_lds16(srcB[3] + kt2, B_c + ldsOff[3]);
    }
    __builtin_amdgcn_s_barrier();
    __builtin_amdgcn_s_setprio(1);
#pragma unroll
    for (int m = 0; m < 4; m++)
#pragma unroll
      for (int n = 0; n < 2; n++)
#pragma unroll
        for (int k = 0; k < 2; k++)
          acc[m + 4][n] = __builtin_amdgcn_mfma_f32_16x16x32_bf16(ahi[m][k], bfr[n][k], acc[m + 4][n], 0, 0, 0);
    __builtin_amdgcn_s_setprio(0);
    __builtin_amdgcn_s_barrier();

    // ---- ph3 ----
    if (st) {
      gload_lds16(srcA[1] + kt2, A_c + ldsOff[1]);
      gload_lds16(srcA[3] + kt2, A_c + ldsOff[3]);
    }
    __builtin_amdgcn_s_barrier();
    __builtin_amdgcn_s_setprio(1);
#pragma unroll
    for (int m = 0; m < 4; m++)
#pragma unroll
      for (int n = 2; n < 4; n++)
#pragma unroll
        for (int k = 0; k < 2; k++)
          acc[m + 4][n] = __builtin_amdgcn_mfma_f32_16x16x32_bf16(ahi[m][k], bfr[n][k], acc[m + 4][n], 0, 0, 0);
    __builtin_amdgcn_s_setprio(0);
    __builtin_amdgcn_s_barrier();
  }
#undef RD

  // ---- fused epilogue via per-wave LDS staging (coalesced stores) ----
  __syncthreads();
  bf16_t* myLds = (wid < 4) ? ((bf16_t*)As + wid * 8192) : ((bf16_t*)Bs + (wid - 4) * 8192);

  const int w = bn * 4 + wn;
  const int typ = w % 3;
  const int head = w / 3;
  const int rowbase = bm * 256 + wm * 128;
  const int b = rowbase >> 11;
  const int s0w = rowbase & (S_ - 1);

  if (typ == 2) {
#pragma unroll
    for (int m = 0; m < 8; m++) {
      int sl0 = m * 16 + g * 4;
#pragma unroll
      for (int n = 0; n < 4; n++) {
        int d = n * 16 + qr;
#pragma unroll
        for (int rr = 0; rr < 4; rr++) {
          int sl = sl0 + rr;
          myLds[d * 128 + (((sl >> 3) ^ (d & 15)) * 8) + (sl & 7)] = (__bf16)acc[m][n][rr];
        }
      }
    }
    bf16_t* dstv = Vtd + (size_t)(b * H_ + head) * HD_ * S_ + s0w;
#pragma unroll
    for (int it = 0; it < 16; it++) {
      int d = (lane >> 4) + it * 4;
      int sc = lane & 15;
      bf16x8 v = *(const bf16x8*)(myLds + d * 128 + ((sc ^ (d & 15)) * 8));
      *(bf16x8*)(dstv + (size_t)d * S_ + sc * 8) = v;
    }
  } else {
    const float qs = (typ == 0) ? 0.125f : 1.0f;
    const float l2r = 13.287712379549449f / 32.0f;
    float inv[2];
    inv[0] = exp2f(-(float)qr * l2r);
    inv[1] = exp2f(-(float)(qr + 16) * l2r);
#pragma unroll
    for (int m = 0; m < 8; m++) {
      int r0 = m * 16 + g * 4;
#pragma unroll
      for (int rr = 0; rr < 4; rr++) {
        int r = r0 + rr;
        float p = (float)pos[rowbase + r];
#pragma unroll
        for (int n = 0; n < 2; n++) {
          float ang = p * inv[n];
          float sn = __sinf(ang);
          float cs = __cosf(ang);
          float x1 = acc[m][n][rr], x2 = acc[m][n + 2][rr];
          float o1 = (x1 * cs - x2 * sn) * qs;
          float o2 = (x2 * cs + x1 * sn) * qs;
          int d1 = n * 16 + qr, d2 = d1 + 32;
          myLds[r * 64 + (((d1 >> 3) ^ (r & 7)) * 8) + (d1 & 7)] = (__bf16)o1;
          myLds[r * 64 + (((d2 >> 3) ^ (r & 7)) * 8) + (d2 & 7)] = (__bf16)o2;
        }
      }
    }
    bf16_t* dstb = ((typ == 0) ? Qd : Kd) + (size_t)(b * H_ + head) * S_ * HD_ + (size_t)s0w * HD_;
#pragma unroll
    for (int it = 0; it < 16; it++) {
      int r = (lane >> 3) + it * 8;
      int cc = lane & 7;
      bf16x8 v = *(const bf16x8*)(myLds + r * 64 + ((cc ^ (r & 7)) * 8));
      *(bf16x8*)(dstb + (size_t)r * HD_ + cc * 8) = v;
    }
  }
}

// ---------------- flash attention: split-KV x4 chunks + XCD-resident KV mapping ----------------
__global__ __launch_bounds__(256) void attn_kernel(const bf16_t* __restrict__ Q,
                                                   const bf16_t* __restrict__ K,
                                                   const bf16_t* __restrict__ Vt,
                                                   const int* __restrict__ pos,
                                                   bf16_t* __restrict__ O,
                                                   bf16_t* __restrict__ Op0,
                                                   bf16_t* __restrict__ Op3,
                                                   float* __restrict__ Mst,
                                                   float* __restrict__ Lst) {
  __shared__ bf16_t Ks[2][64 * 64];
  __shared__ bf16_t Vs[2][64 * 64];

  const int t = threadIdx.x;
  const int lane = t & 63, wv = t >> 6;
  const int l31 = lane & 31, hi = lane >> 5;

  const int bid = blockIdx.x;
  const int bh = (bid & 7) * 4 + ((bid >> 3) & 3);
  const int v6 = bid >> 5;
  const int qblk = 15 - (v6 >> 2);
  const int chunk = v6 & 3;
  const int b = bh >> 4, h = bh & 15;
  const int q0 = qblk * 128;

  const bf16_t* Qb = Q + (size_t)bh * (S_ * HD_);
  const bf16_t* Kb = K + (size_t)bh * (S_ * HD_);
  const bf16_t* Vb = Vt + (size_t)bh * (HD_ * S_);

  const int qrow = q0 + wv * 32 + l31;

  const int prow = pos[b * S_ + qrow];
  int wmin = prow;
#pragma unroll
  for (int off = 1; off < 32; off <<= 1) wmin = min(wmin, __shfl_xor(wmin, off));

  int mp = max(pos[b * S_ + q0 + lane], pos[b * S_ + q0 + 64 + lane]);
#pragma unroll
  for (int off = 1; off < 64; off <<= 1) mp = max(mp, __shfl_xor(mp, off));
  const int nt = min(S_ / KVBLK, (mp >> 6) + 1);

  const int t0 = chunk * CHTILES;
  const int t1 = min(nt, t0 + CHTILES);
  if (t0 >= t1) return;
  const bool needs_merge = (nt > CHTILES);

  bf16x8 qf[4];
#pragma unroll
  for (int c = 0; c < 4; c++)
    qf[c] = *(const bf16x8*)(Qb + (size_t)qrow * HD_ + c * 16 + hi * 8);

  const int r0 = t >> 3, c0 = t & 7;
  const int r1 = (t + 256) >> 3, c1 = t & 7;
  const bf16_t* KgA = Kb + (size_t)r0 * HD_ + ((c0 ^ (r0 & 7)) * 8);
  const bf16_t* KgB = Kb + (size_t)r1 * HD_ + ((c1 ^ (r1 & 7)) * 8);
  const bf16_t* VgA = Vb + (size_t)r0 * S_ + ((c0 ^ (r0 & 7)) * 8);
  const bf16_t* VgB = Vb + (size_t)r1 * S_ + ((c1 ^ (r1 & 7)) * 8);
  const int ldsA = t * 8, ldsB = (t + 256) * 8;

  f32x16 oT[2];
#pragma unroll
  for (int dt = 0; dt < 2; dt++)
#pragma unroll
    for (int r = 0; r < 16; r++) oT[dt][r] = 0.f;
  float m_run = NINF, l_run = 0.f;

  {
    const int kn = t0 * KVBLK;
    gload_lds16(KgA + (size_t)kn * HD_, Ks[0] + ldsA);
    gload_lds16(KgB + (size_t)kn * HD_, Ks[0] + ldsB);
    gload_lds16(VgA + kn, Vs[0] + ldsA);
    gload_lds16(VgB + kn, Vs[0] + ldsB);
  }
  __syncthreads();

  for (int kt = t0; kt < t1; ++kt) {
    const int k0 = kt * KVBLK;
    const int cur = kt & 1;
    if (kt + 1 < t1) {
      const int kn = (kt + 1) * KVBLK;
      gload_lds16(KgA + (size_t)kn * HD_, Ks[cur ^ 1] + ldsA);
      gload_lds16(KgB + (size_t)kn * HD_, Ks[cur ^ 1] + ldsB);
      gload_lds16(VgA + kn, Vs[cur ^ 1] + ldsA);
      gload_lds16(VgB + kn, Vs[cur ^ 1] + ldsB);
    }
    const bf16_t* Kc = Ks[cur];
    const bf16_t* Vc = Vs[cur];

    f32x16 s0, s1;
#pragma unroll
    for (int r = 0; r < 16; r++) { s0[r] = 0.f; s1[r] = 0.f; }
    __builtin_amdgcn_s_setprio(1);
#pragma unroll
    for (int c = 0; c < 4; c++) {
      const int c2 = c * 2 + hi;
      const int kr0 = l31;
      const int kr1 = 32 + l31;
      bf16x8 kf0 = *(const bf16x8*)(Kc + kr0 * 64 + ((c2 ^ (kr0 & 7)) * 8));
      bf16x8 kf1 = *(const bf16x8*)(Kc + kr1 * 64 + ((c2 ^ (kr1 & 7)) * 8));
      s0 = __builtin_amdgcn_mfma_f32_32x32x16_bf16(kf0, qf[c], s0, 0, 0, 0);
      s1 = __builtin_amdgcn_mfma_f32_32x32x16_bf16(kf1, qf[c], s1, 0, 0, 0);
    }
    __builtin_amdgcn_s_setprio(0);

    float p0[16], p1[16];
    if (k0 + 63 > wmin) {
#pragma unroll
      for (int r = 0; r < 16; r++) {
        int koff = (r & 3) + 8 * (r >> 2) + 4 * hi;
        p0[r] = (k0 + koff <= prow) ? s0[r] : NINF;
        p1[r] = (k0 + 32 + koff <= prow) ? s1[r] : NINF;
      }
    } else {
#pragma unroll
      for (int r = 0; r < 16; r++) { p0[r] = s0[r]; p1[r] = s1[r]; }
    }

    float tm = NINF;
#pragma unroll
    for (int r = 0; r < 16; r++) tm = fmaxf(tm, fmaxf(p0[r], p1[r]));
    tm = fmaxf(tm, __shfl_xor(tm, 32));
    if (__any(tm > m_run + 8.0f)) {
      float mn = fmaxf(fmaxf(m_run, tm), -1e30f);
      float scale = exp2f((m_run - mn) * L2E);
      l_run *= scale;
#pragma unroll
      for (int dt = 0; dt < 2; dt++)
#pragma unroll
        for (int r = 0; r < 16; r++) oT[dt][r] *= scale;
      m_run = mn;
    }
    const float mnl = (m_run == NINF) ? 3.0e38f : m_run * L2E;
    float rs = 0.f;
#pragma unroll
    for (int r = 0; r < 16; r++) {
      p0[r] = exp2f(p0[r] * L2E - mnl);
      p1[r] = exp2f(p1[r] * L2E - mnl);
      rs += p0[r] + p1[r];
    }
    rs += __shfl_xor(rs, 32);
    l_run += rs;

#pragma unroll
    for (int kc = 0; kc < 4; kc++) {
      const float* P = (kc < 2) ? p0 : p1;
      const int rb = (kc & 1) * 8;
      uint32_t xa0 = packbf(P[rb + 0], P[rb + 1]);
      uint32_t xa1 = packbf(P[rb + 2], P[rb + 3]);
      uint32_t xb0 = packbf(P[rb + 4], P[rb + 5]);
      uint32_t xb1 = packbf(P[rb + 6], P[rb + 7]);
      uint32_t sa0 = (uint32_t)__shfl_xor((int)xa0, 32);
      uint32_t sa1 = (uint32_t)__shfl_xor((int)xa1, 32);
      uint32_t sb0 = (uint32_t)__shfl_xor((int)xb0, 32);
      uint32_t sb1 = (uint32_t)__shfl_xor((int)xb1, 32);
      union { uint32_t u[4]; bf16x8 v; } pf;
      pf.u[0] = hi ? sb0 : xa0;
      pf.u[1] = hi ? sb1 : xa1;
      pf.u[2] = hi ? xb0 : sa0;
      pf.u[3] = hi ? xb1 : sa1;
      __builtin_amdgcn_s_setprio(1);
#pragma unroll
      for (int dt = 0; dt < 2; dt++) {
        const int vr = dt * 32 + l31;
        const int c2 = kc * 2 + hi;
        bf16x8 vf = *(const bf16x8*)(Vc + vr * 64 + ((c2 ^ (vr & 7)) * 8));
        oT[dt] = __builtin_amdgcn_mfma_f32_32x32x16_bf16(vf, pf.v, oT[dt], 0, 0, 0);
      }
      __builtin_amdgcn_s_setprio(0);
    }

    __syncthreads();
  }

  const float rl = needs_merge ? 1.0f : ((l_run > 0.f) ? 1.0f / l_run : 0.f);
  bf16_t* Ot = (bf16_t*)Ks + wv * 2048;
#pragma unroll
  for (int dt = 0; dt < 2; dt++)
#pragma unroll
    for (int r = 0; r < 16; r++) {
      int chunkq = dt * 4 + (r >> 2);
      int el = (r & 3) + 4 * hi;
      Ot[l31 * 64 + ((chunkq ^ (l31 & 7)) * 8) + el] = (__bf16)(oT[dt][r] * rl);
    }
  __syncthreads();
  if (needs_merge) {
    bf16_t* dst = ((chunk < 3) ? (Op0 + (size_t)chunk * CHELEMS) : Op3)
                + ((size_t)(bh * 16 + qblk) * 128) * 64;
#pragma unroll
    for (int it = 0; it < 4; it++) {
      int qr2 = (lane >> 3) + it * 8;
      int cc = lane & 7;
      bf16x8 vv = *(const bf16x8*)(Ot + qr2 * 64 + ((cc ^ (qr2 & 7)) * 8));
      *(bf16x8*)(&dst[(size_t)(wv * 32 + qr2) * 64 + cc * 8]) = vv;
    }
    if (hi == 0) {
      size_t sidx = ((size_t)(chunk * 32 + bh) * 16 + qblk) * 128 + wv * 32 + l31;
      Mst[sidx] = m_run;
      Lst[sidx] = l_run;
    }
  } else {
#pragma unroll
    for (int it = 0; it < 4; it++) {
      int qr2 = (lane >> 3) + it * 8;
      int cc = lane & 7;
      bf16x8 vv = *(const bf16x8*)(Ot + qr2 * 64 + ((cc ^ (qr2 & 7)) * 8));
      *(bf16x8*)(&O[(size_t)(b * S_ + q0 + wv * 32 + qr2) * D_ + h * 64 + cc * 8]) = vv;
    }
  }
}

// ---------------- split-KV merge over nch = ceil(nt/8) chunks ----------------
__global__ __launch_bounds__(256) void attn_merge_kernel(const bf16_t* __restrict__ Op0,
                                                         const bf16_t* __restrict__ Op3,
                                                         const float* __restrict__ Mst,
                                                         const float* __restrict__ Lst,
                                                         const int* __restrict__ pos,
                                                         bf16_t* __restrict__ O) {
  __shared__ int wmax_s[4];
  const int t = threadIdx.x;
  const int bid = blockIdx.x;
  const int bh = (bid & 7) * 4 + ((bid >> 3) & 3);
  const int qblk = 15 - (bid >> 5);
  const int b = bh >> 4, h = bh & 15;
  const int q0 = qblk * 128;

  int p = pos[b * S_ + q0 + (t & 127)];
#pragma unroll
  for (int off = 1; off < 64; off <<= 1) p = max(p, __shfl_xor(p, off));
  if ((t & 63) == 0) wmax_s[t >> 6] = p;
  __syncthreads();
  int mp = max(max(wmax_s[0], wmax_s[1]), max(wmax_s[2], wmax_s[3]));
  const int nt = min(S_ / KVBLK, (mp >> 6) + 1);
  const int nch = (nt + CHTILES - 1) / CHTILES;
  if (nch <= 1) return;

  const int r = t >> 1, dh = (t & 1) * 32;
  const size_t rowoff = ((size_t)(bh * 16 + qblk) * 128 + r) * 64 + dh;

  float mc[4], lc[4];
  float m = -1e30f;
  for (int c = 0; c < nch; c++) {
    size_t sidx = ((size_t)(c * 32 + bh) * 16 + qblk) * 128 + r;
    mc[c] = Mst[sidx];
    lc[c] = Lst[sidx];
    m = fmaxf(m, mc[c]);
  }
  float accv[32];
#pragma unroll
  for (int j = 0; j < 32; j++) accv[j] = 0.f;
  float lt = 0.f;
  for (int c = 0; c < nch; c++) {
    float wgt = exp2f((mc[c] - m) * L2E);
    lt += lc[c] * wgt;
    const bf16_t* pc = ((c < 3) ? (Op0 + (size_t)c * CHELEMS) : Op3) + rowoff;
#pragma unroll
    for (int cc4 = 0; cc4 < 4; cc4++) {
      bf16x8 v = *(const bf16x8*)(pc + cc4 * 8);
#pragma unroll
      for (int j = 0; j < 8; j++) accv[cc4 * 8 + j] += wgt * (float)v[j];
    }
  }
  const float rl = (lt > 0.f) ? 1.0f / lt : 0.f;
  bf16_t* dst = O + (size_t)(b * S_ + q0 + r) * D_ + h * 64 + dh;
#pragma unroll
  for (int cc4 = 0; cc4 < 4; cc4++) {
    bf16x8 o;
#pragma unroll
    for (int j = 0; j < 8; j++) o[j] = (__bf16)(accv[cc4 * 8 + j] * rl);
    *(bf16x8*)(dst + cc4 * 8) = o;
  }
}

extern "C" void kernel_launch(void* const* d_in, const int* in_sizes, int n_in,
                              void* d_out, int out_size, void* d_ws, size_t ws_size,
                              hipStream_t stream) {
  const float* inputs = (const float*)d_in[0];
  const int* positions = (const int*)d_in[1];
  const float* W_in = (const float*)d_in[2];
  const float* W_out = (const float*)d_in[3];
  float* out = (float*)d_out;

  bf16_t* X_bf = (bf16_t*)d_ws;                       // 4096*1024 (dead after qkv-gemm)
  bf16_t* Win_bf = X_bf + (size_t)4096 * 1024;        // 3072*1024 (dead after qkv-gemm)
  bf16_t* Wout_bf = Win_bf + (size_t)3072 * 1024;     // live until gemm2
  bf16_t* scratch = Wout_bf + (size_t)1024 * 1024;    // 4096*3072 (dead: qkv never stored)
  bf16_t* Qb = scratch + (size_t)4096 * 3072;
  bf16_t* Kb = Qb + (size_t)B_ * H_ * S_ * HD_;
  bf16_t* Vtb = Kb + (size_t)B_ * H_ * S_ * HD_;
  bf16_t* Ob = Vtb + (size_t)B_ * H_ * S_ * HD_;

  bf16_t* Op0 = scratch;
  bf16_t* Op3 = X_bf;
  float* Mst = (float*)Win_bf;
  float* Lst = Mst + (size_t)4 * 32 * 16 * 128;

  cast3_bf16_kernel<<<dim3(2048), dim3(256), 0, stream>>>(
      inputs, X_bf, (4096 * 1024) / 4,
      W_in, Win_bf, (3072 * 1024) / 4,
      W_out, Wout_bf, (1024 * 1024) / 4);

  gemm_qkv_rope<<<dim3(192), dim3(512), 0, stream>>>(X_bf, Win_bf, positions, Qb, Kb, Vtb);

  attn_kernel<<<dim3(2048), dim3(256), 0, stream>>>(Qb, Kb, Vtb, positions, Ob, Op0, Op3, Mst, Lst);
  attn_merge_kernel<<<dim3(512), dim3(256), 0, stream>>>(Op0, Op3, Mst, Lst, positions, Ob);

  gemm_bt64<float><<<dim3(512), dim3(256), 0, stream>>>(Ob, Wout_bf, out, 4096, 1024, 1024);
}

// Round 18
// 133.468 us; speedup vs baseline: 1.3507x; 1.0199x over previous
//
#include <hip/hip_runtime.h>
#include <stdint.h>
#include <math.h>

#define B_ 2
#define S_ 2048
#define D_ 1024
#define H_ 16
#define HD_ 64
#define KVBLK 64
#define CHTILES 8                 // kv tiles per split chunk
#define CHELEMS ((size_t)32 * 16 * 128 * 64)   // bf16 elems per chunk partial

typedef __bf16 bf16_t;
typedef __bf16 bf16x4 __attribute__((ext_vector_type(4)));
typedef __bf16 bf16x8 __attribute__((ext_vector_type(8)));
typedef float f32x4 __attribute__((ext_vector_type(4)));
typedef float f32x16 __attribute__((ext_vector_type(16)));
typedef float float4v __attribute__((ext_vector_type(4)));

#define L2E 1.4426950408889634f
#define NINF (-__builtin_inff())

__device__ __forceinline__ void gload_lds16(const bf16_t* g, bf16_t* l) {
  __builtin_amdgcn_global_load_lds((const __attribute__((address_space(1))) void*)g,
                                   (__attribute__((address_space(3))) void*)l, 16, 0, 0);
}

__device__ __forceinline__ uint32_t packbf(float a, float b) {
  union { __bf16 h[2]; uint32_t u; } cvt;
  cvt.h[0] = (__bf16)a; cvt.h[1] = (__bf16)b;
  return cvt.u;
}

// ---------------- fused cast f32 -> bf16 for all three inputs (vector x4) ----------------
__global__ void cast3_bf16_kernel(const float* __restrict__ s0, bf16_t* __restrict__ d0, int n0,
                                  const float* __restrict__ s1, bf16_t* __restrict__ d1, int n1,
                                  const float* __restrict__ s2, bf16_t* __restrict__ d2, int n2) {
  int i = blockIdx.x * blockDim.x + threadIdx.x;
  int stride = gridDim.x * blockDim.x;
  int tot = n0 + n1 + n2;
  for (; i < tot; i += stride) {
    const float* s; bf16_t* d; int j = i;
    if (j < n0) { s = s0; d = d0; }
    else if ((j -= n0) < n1) { s = s1; d = d1; }
    else { j -= n1; s = s2; d = d2; }
    float4v f = *(const float4v*)(s + (size_t)j * 4);
    bf16x4 o;
    o[0] = (__bf16)f[0]; o[1] = (__bf16)f[1]; o[2] = (__bf16)f[2]; o[3] = (__bf16)f[3];
    *(bf16x4*)(d + (size_t)j * 4) = o;
  }
}

// ------- gemm2: 128x64-tile GEMM, XCD-quadrant swizzle + 2-phase LDS dbuf (T3 minimum) -------
// Prefetch tile kk+32 into buf^1 BEFORE computing tile kk; single __syncthreads per iter
// drains prefetch a full compute-phase after issue (attn-proven pattern). LDS 24KB -> >=2 blk/CU.
template <typename OutT>
__global__ __launch_bounds__(256) void gemm_bt64(const bf16_t* __restrict__ A,
                                                 const bf16_t* __restrict__ Bm,
                                                 OutT* __restrict__ C,
                                                 int M, int N, int K) {
  __shared__ bf16_t As[2][128 * 32];   // 2 x 8KB
  __shared__ bf16_t Bs[2][64 * 32];    // 2 x 4KB
  const int t = threadIdx.x;
  const int lane = t & 63, wave = t >> 6;
  const int wr = wave >> 1, wc = wave & 1;
  const int qr = lane & 15, g = lane >> 4;
  const int bid = blockIdx.x;
  const int xcd = bid & 7, local = bid >> 3;
  const int bm = ((xcd >> 1) << 3) + (local & 7);
  const int bn = ((xcd & 1) << 3) + (local >> 3);

  f32x4 acc[4][2];
#pragma unroll
  for (int m = 0; m < 4; m++)
#pragma unroll
    for (int n = 0; n < 2; n++) acc[m][n] = (f32x4){0.f, 0.f, 0.f, 0.f};

  const bf16_t* Abase = A + (size_t)(bm * 128) * K;
  const bf16_t* Bbase = Bm + (size_t)(bn * 64) * K;
  const int srow = t >> 2;            // 0..63
  const int scol = (t & 3) * 8;
  const bf16_t* Ag0 = Abase + (size_t)srow * K + scol;
  const bf16_t* Ag1 = Abase + (size_t)(srow + 64) * K + scol;
  const bf16_t* Bg0 = Bbase + (size_t)srow * K + scol;

  // prologue: stage tile 0 into buf 0
  gload_lds16(Ag0, As[0] + t * 8);
  gload_lds16(Ag1, As[0] + 2048 + t * 8);
  gload_lds16(Bg0, Bs[0] + t * 8);
  __syncthreads();

  const int NT = K >> 5;
  for (int T = 0; T < NT; ++T) {
    const int cur = T & 1;
    if (T + 1 < NT) {
      const int kn = (T + 1) * 32;
      gload_lds16(Ag0 + kn, As[cur ^ 1] + t * 8);
      gload_lds16(Ag1 + kn, As[cur ^ 1] + 2048 + t * 8);
      gload_lds16(Bg0 + kn, Bs[cur ^ 1] + t * 8);
    }
    const bf16_t* Ac = As[cur];
    const bf16_t* Bc = Bs[cur];
    bf16x8 a[4], b[2];
#pragma unroll
    for (int m = 0; m < 4; m++)
      a[m] = *(const bf16x8*)(Ac + (wr * 64 + m * 16 + qr) * 32 + g * 8);
#pragma unroll
    for (int n = 0; n < 2; n++)
      b[n] = *(const bf16x8*)(Bc + (wc * 32 + n * 16 + qr) * 32 + g * 8);
    __builtin_amdgcn_s_setprio(1);
#pragma unroll
    for (int m = 0; m < 4; m++)
#pragma unroll
      for (int n = 0; n < 2; n++)
        acc[m][n] = __builtin_amdgcn_mfma_f32_16x16x32_bf16(a[m], b[n], acc[m][n], 0, 0, 0);
    __builtin_amdgcn_s_setprio(0);
    __syncthreads();   // drains this iter's prefetch (issued pre-compute) + joins waves
  }

#pragma unroll
  for (int m = 0; m < 4; m++) {
    int row0 = bm * 128 + wr * 64 + m * 16 + g * 4;
#pragma unroll
    for (int n = 0; n < 2; n++) {
      int col = bn * 64 + wc * 32 + n * 16 + qr;
#pragma unroll
      for (int r = 0; r < 4; r++)
        C[(size_t)(row0 + r) * N + col] = (OutT)acc[m][n][r];
    }
  }
}

// ---- fused QKV GEMM + RoPE + q-scale + V-transpose; XCD-quadrant swizzle (R17) ----
__global__ __launch_bounds__(512, 1) void gemm_qkv_rope(const bf16_t* __restrict__ A,
                                                        const bf16_t* __restrict__ Bm,
                                                        const int* __restrict__ pos,
                                                        bf16_t* __restrict__ Qd,
                                                        bf16_t* __restrict__ Kd,
                                                        bf16_t* __restrict__ Vtd) {
  const int K = D_;
  const int NT = K >> 6;
  __shared__ bf16_t As[2][256 * 64];
  __shared__ bf16_t Bs[2][256 * 64];
  const int t = threadIdx.x;
  const int lane = t & 63, wid = t >> 6;
  const int qr = lane & 15, g = lane >> 4;
  const int wm = wid >> 2, wn = wid & 3;
  const int bid = blockIdx.x;
  const int xcd = bid & 7, local = bid >> 3;
  const int bm = (xcd >> 1) * 4 + (local & 3);
  const int bn = (xcd & 1) * 6 + (local >> 2);

  const bf16_t* Ab = A + (size_t)(bm * 256) * K;
  const bf16_t* Bb = Bm + (size_t)(bn * 256) * K;

  const bf16_t* srcA[4];
  const bf16_t* srcB[4];
  int ldsOff[4];
#pragma unroll
  for (int i = 0; i < 4; i++) {
    int e = t + 512 * i;
    int row = e >> 3, cs = e & 7;
    int gcol = (cs ^ (row & 7)) * 8;
    srcA[i] = Ab + (size_t)row * K + gcol;
    srcB[i] = Bb + (size_t)row * K + gcol;
    ldsOff[i] = e * 8;
  }

  f32x4 acc[8][4];
#pragma unroll
  for (int m = 0; m < 8; m++)
#pragma unroll
    for (int n = 0; n < 4; n++) acc[m][n] = (f32x4){0.f, 0.f, 0.f, 0.f};

#define RD(buf_, r_, k_) (*(const bf16x8*)((buf_) + (r_) * 64 + ((((k_) * 4 + g) ^ ((r_) & 7)) * 8)))

#pragma unroll
  for (int i = 0; i < 4; i++) gload_lds16(srcA[i], As[0] + ldsOff[i]);
#pragma unroll
  for (int i = 0; i < 4; i++) gload_lds16(srcB[i], Bs[0] + ldsOff[i]);
#pragma unroll
  for (int i = 0; i < 4; i++) gload_lds16(srcA[i] + 64, As[1] + ldsOff[i]);
#pragma unroll
  for (int i = 0; i < 4; i++) gload_lds16(srcB[i] + 64, Bs[1] + ldsOff[i]);

  for (int T = 0; T < NT; ++T) {
    bf16_t* A_c = As[T & 1];
    bf16_t* B_c = Bs[T & 1];
    if (T + 1 < NT) asm volatile("s_waitcnt vmcnt(8)" ::: "memory");
    else            asm volatile("s_waitcnt vmcnt(0)" ::: "memory");
    __builtin_amdgcn_sched_barrier(0);
    __builtin_amdgcn_s_barrier();

    const bool st = (T + 2 < NT);
    const int kt2 = (T + 2) * 64;

    bf16x8 alo[4][2], ahi[4][2], bfr[4][2];

    // ---- ph0 ----
#pragma unroll
    for (int m = 0; m < 4; m++) {
      int r = wm * 128 + m * 16 + qr;
      alo[m][0] = RD(A_c, r, 0); alo[m][1] = RD(A_c, r, 1);
    }
#pragma unroll
    for (int n = 0; n < 2; n++) {
      int r = wn * 64 + n * 16 + qr;
      bfr[n][0] = RD(B_c, r, 0); bfr[n][1] = RD(B_c, r, 1);
    }
    __builtin_amdgcn_s_barrier();
    __builtin_amdgcn_s_setprio(1);
#pragma unroll
    for (int m = 0; m < 4; m++)
#pragma unroll
      for (int n = 0; n < 2; n++)
#pragma unroll
        for (int k = 0; k < 2; k++)
          acc[m][n] = __builtin_amdgcn_mfma_f32_16x16x32_bf16(alo[m][k], bfr[n][k], acc[m][n], 0, 0, 0);
    __builtin_amdgcn_s_setprio(0);
    __builtin_amdgcn_s_barrier();

    // ---- ph1 ----
#pragma unroll
    for (int n = 2; n < 4; n++) {
      int r = wn * 64 + n * 16 + qr;
      bfr[n][0] = RD(B_c, r, 0); bfr[n][1] = RD(B_c, r, 1);
    }
    if (st) {
      gload_lds16(srcA[0] + kt2, A_c + ldsOff[0]);
      gload_lds16(srcA[2] + kt2, A_c + ldsOff[2]);
    }
    __builtin_amdgcn_s_barrier();
    __builtin_amdgcn_s_setprio(1);
#pragma unroll
    for (int m = 0; m < 4; m++)
#pragma unroll
      for (int n = 2; n < 4; n++)
#pragma unroll
        for (int k = 0; k < 2; k++)
          acc[m][n] = __builtin_amdgcn_mfma_f32_16x16x32_bf16(alo[m][k], bfr[n][k], acc[m][n], 0, 0, 0);
    __builtin_amdgcn_s_setprio(0);
    __builtin_amdgcn_s_barrier();

    // ---- ph2 ----
#pragma unroll
    for (int m = 0; m < 4; m++) {
      int r = wm * 128 + (m + 4) * 16 + qr;
      ahi[m][0] = RD(A_c, r, 0); ahi[m][1] = RD(A_c, r, 1);
    }
    if (st) {
      gload_lds16(srcB[0] + kt2, B_c + ldsOff[0]);
      gload_lds16(srcB[1] + kt2, B_c + ldsOff[1]);
      gload_lds16(srcB[2] + kt2, B_c + ldsOff[2]);
      gload_lds16(srcB[3] + kt2, B_c + ldsOff[3]);
    }
    __builtin_amdgcn_s_barrier();
    __builtin_amdgcn_s_setprio(1);
#pragma unroll
    for (int m = 0; m < 4; m++)
#pragma unroll
      for (int n = 0; n < 2; n++)
#pragma unroll
        for (int k = 0; k < 2; k++)
          acc[m + 4][n] = __builtin_amdgcn_mfma_f32_16x16x32_bf16(ahi[m][k], bfr[n][k], acc[m + 4][n], 0, 0, 0);
    __builtin_amdgcn_s_setprio(0);
    __builtin_amdgcn_s_barrier();

    // ---- ph3 ----
    if (st) {
      gload_lds16(srcA[1] + kt2, A_c + ldsOff[1]);
      gload_lds16(srcA[3] + kt2, A_c + ldsOff[3]);
    }
    __builtin_amdgcn_s_barrier();
    __builtin_amdgcn_s_setprio(1);
#pragma unroll
    for (int m = 0; m < 4; m++)
#pragma unroll
      for (int n = 2; n < 4; n++)
#pragma unroll
        for (int k = 0; k < 2; k++)
          acc[m + 4][n] = __builtin_amdgcn_mfma_f32_16x16x32_bf16(ahi[m][k], bfr[n][k], acc[m + 4][n], 0, 0, 0);
    __builtin_amdgcn_s_setprio(0);
    __builtin_amdgcn_s_barrier();
  }
#undef RD

  // ---- fused epilogue via per-wave LDS staging (coalesced stores) ----
  __syncthreads();
  bf16_t* myLds = (wid < 4) ? ((bf16_t*)As + wid * 8192) : ((bf16_t*)Bs + (wid - 4) * 8192);

  const int w = bn * 4 + wn;
  const int typ = w % 3;
  const int head = w / 3;
  const int rowbase = bm * 256 + wm * 128;
  const int b = rowbase >> 11;
  const int s0w = rowbase & (S_ - 1);

  if (typ == 2) {
#pragma unroll
    for (int m = 0; m < 8; m++) {
      int sl0 = m * 16 + g * 4;
#pragma unroll
      for (int n = 0; n < 4; n++) {
        int d = n * 16 + qr;
#pragma unroll
        for (int rr = 0; rr < 4; rr++) {
          int sl = sl0 + rr;
          myLds[d * 128 + (((sl >> 3) ^ (d & 15)) * 8) + (sl & 7)] = (__bf16)acc[m][n][rr];
        }
      }
    }
    bf16_t* dstv = Vtd + (size_t)(b * H_ + head) * HD_ * S_ + s0w;
#pragma unroll
    for (int it = 0; it < 16; it++) {
      int d = (lane >> 4) + it * 4;
      int sc = lane & 15;
      bf16x8 v = *(const bf16x8*)(myLds + d * 128 + ((sc ^ (d & 15)) * 8));
      *(bf16x8*)(dstv + (size_t)d * S_ + sc * 8) = v;
    }
  } else {
    const float qs = (typ == 0) ? 0.125f : 1.0f;
    const float l2r = 13.287712379549449f / 32.0f;
    float inv[2];
    inv[0] = exp2f(-(float)qr * l2r);
    inv[1] = exp2f(-(float)(qr + 16) * l2r);
#pragma unroll
    for (int m = 0; m < 8; m++) {
      int r0 = m * 16 + g * 4;
#pragma unroll
      for (int rr = 0; rr < 4; rr++) {
        int r = r0 + rr;
        float p = (float)pos[rowbase + r];
#pragma unroll
        for (int n = 0; n < 2; n++) {
          float ang = p * inv[n];
          float sn = __sinf(ang);
          float cs = __cosf(ang);
          float x1 = acc[m][n][rr], x2 = acc[m][n + 2][rr];
          float o1 = (x1 * cs - x2 * sn) * qs;
          float o2 = (x2 * cs + x1 * sn) * qs;
          int d1 = n * 16 + qr, d2 = d1 + 32;
          myLds[r * 64 + (((d1 >> 3) ^ (r & 7)) * 8) + (d1 & 7)] = (__bf16)o1;
          myLds[r * 64 + (((d2 >> 3) ^ (r & 7)) * 8) + (d2 & 7)] = (__bf16)o2;
        }
      }
    }
    bf16_t* dstb = ((typ == 0) ? Qd : Kd) + (size_t)(b * H_ + head) * S_ * HD_ + (size_t)s0w * HD_;
#pragma unroll
    for (int it = 0; it < 16; it++) {
      int r = (lane >> 3) + it * 8;
      int cc = lane & 7;
      bf16x8 v = *(const bf16x8*)(myLds + r * 64 + ((cc ^ (r & 7)) * 8));
      *(bf16x8*)(dstb + (size_t)r * HD_ + cc * 8) = v;
    }
  }
}

// ---------------- flash attention: split-KV x4 chunks + XCD-resident KV mapping ----------------
__global__ __launch_bounds__(256) void attn_kernel(const bf16_t* __restrict__ Q,
                                                   const bf16_t* __restrict__ K,
                                                   const bf16_t* __restrict__ Vt,
                                                   const int* __restrict__ pos,
                                                   bf16_t* __restrict__ O,
                                                   bf16_t* __restrict__ Op0,
                                                   bf16_t* __restrict__ Op3,
                                                   float* __restrict__ Mst,
                                                   float* __restrict__ Lst) {
  __shared__ bf16_t Ks[2][64 * 64];
  __shared__ bf16_t Vs[2][64 * 64];

  const int t = threadIdx.x;
  const int lane = t & 63, wv = t >> 6;
  const int l31 = lane & 31, hi = lane >> 5;

  const int bid = blockIdx.x;
  const int bh = (bid & 7) * 4 + ((bid >> 3) & 3);
  const int v6 = bid >> 5;
  const int qblk = 15 - (v6 >> 2);
  const int chunk = v6 & 3;
  const int b = bh >> 4, h = bh & 15;
  const int q0 = qblk * 128;

  const bf16_t* Qb = Q + (size_t)bh * (S_ * HD_);
  const bf16_t* Kb = K + (size_t)bh * (S_ * HD_);
  const bf16_t* Vb = Vt + (size_t)bh * (HD_ * S_);

  const int qrow = q0 + wv * 32 + l31;

  const int prow = pos[b * S_ + qrow];
  int wmin = prow;
#pragma unroll
  for (int off = 1; off < 32; off <<= 1) wmin = min(wmin, __shfl_xor(wmin, off));

  int mp = max(pos[b * S_ + q0 + lane], pos[b * S_ + q0 + 64 + lane]);
#pragma unroll
  for (int off = 1; off < 64; off <<= 1) mp = max(mp, __shfl_xor(mp, off));
  const int nt = min(S_ / KVBLK, (mp >> 6) + 1);

  const int t0 = chunk * CHTILES;
  const int t1 = min(nt, t0 + CHTILES);
  if (t0 >= t1) return;
  const bool needs_merge = (nt > CHTILES);

  bf16x8 qf[4];
#pragma unroll
  for (int c = 0; c < 4; c++)
    qf[c] = *(const bf16x8*)(Qb + (size_t)qrow * HD_ + c * 16 + hi * 8);

  const int r0 = t >> 3, c0 = t & 7;
  const int r1 = (t + 256) >> 3, c1 = t & 7;
  const bf16_t* KgA = Kb + (size_t)r0 * HD_ + ((c0 ^ (r0 & 7)) * 8);
  const bf16_t* KgB = Kb + (size_t)r1 * HD_ + ((c1 ^ (r1 & 7)) * 8);
  const bf16_t* VgA = Vb + (size_t)r0 * S_ + ((c0 ^ (r0 & 7)) * 8);
  const bf16_t* VgB = Vb + (size_t)r1 * S_ + ((c1 ^ (r1 & 7)) * 8);
  const int ldsA = t * 8, ldsB = (t + 256) * 8;

  f32x16 oT[2];
#pragma unroll
  for (int dt = 0; dt < 2; dt++)
#pragma unroll
    for (int r = 0; r < 16; r++) oT[dt][r] = 0.f;
  float m_run = NINF, l_run = 0.f;

  {
    const int kn = t0 * KVBLK;
    gload_lds16(KgA + (size_t)kn * HD_, Ks[0] + ldsA);
    gload_lds16(KgB + (size_t)kn * HD_, Ks[0] + ldsB);
    gload_lds16(VgA + kn, Vs[0] + ldsA);
    gload_lds16(VgB + kn, Vs[0] + ldsB);
  }
  __syncthreads();

  for (int kt = t0; kt < t1; ++kt) {
    const int k0 = kt * KVBLK;
    const int cur = kt & 1;
    if (kt + 1 < t1) {
      const int kn = (kt + 1) * KVBLK;
      gload_lds16(KgA + (size_t)kn * HD_, Ks[cur ^ 1] + ldsA);
      gload_lds16(KgB + (size_t)kn * HD_, Ks[cur ^ 1] + ldsB);
      gload_lds16(VgA + kn, Vs[cur ^ 1] + ldsA);
      gload_lds16(VgB + kn, Vs[cur ^ 1] + ldsB);
    }
    const bf16_t* Kc = Ks[cur];
    const bf16_t* Vc = Vs[cur];

    f32x16 s0, s1;
#pragma unroll
    for (int r = 0; r < 16; r++) { s0[r] = 0.f; s1[r] = 0.f; }
    __builtin_amdgcn_s_setprio(1);
#pragma unroll
    for (int c = 0; c < 4; c++) {
      const int c2 = c * 2 + hi;
      const int kr0 = l31;
      const int kr1 = 32 + l31;
      bf16x8 kf0 = *(const bf16x8*)(Kc + kr0 * 64 + ((c2 ^ (kr0 & 7)) * 8));
      bf16x8 kf1 = *(const bf16x8*)(Kc + kr1 * 64 + ((c2 ^ (kr1 & 7)) * 8));
      s0 = __builtin_amdgcn_mfma_f32_32x32x16_bf16(kf0, qf[c], s0, 0, 0, 0);
      s1 = __builtin_amdgcn_mfma_f32_32x32x16_bf16(kf1, qf[c], s1, 0, 0, 0);
    }
    __builtin_amdgcn_s_setprio(0);

    float p0[16], p1[16];
    if (k0 + 63 > wmin) {
#pragma unroll
      for (int r = 0; r < 16; r++) {
        int koff = (r & 3) + 8 * (r >> 2) + 4 * hi;
        p0[r] = (k0 + koff <= prow) ? s0[r] : NINF;
        p1[r] = (k0 + 32 + koff <= prow) ? s1[r] : NINF;
      }
    } else {
#pragma unroll
      for (int r = 0; r < 16; r++) { p0[r] = s0[r]; p1[r] = s1[r]; }
    }

    float tm = NINF;
#pragma unroll
    for (int r = 0; r < 16; r++) tm = fmaxf(tm, fmaxf(p0[r], p1[r]));
    tm = fmaxf(tm, __shfl_xor(tm, 32));
    if (__any(tm > m_run + 8.0f)) {
      float mn = fmaxf(fmaxf(m_run, tm), -1e30f);
      float scale = exp2f((m_run - mn) * L2E);
      l_run *= scale;
#pragma unroll
      for (int dt = 0; dt < 2; dt++)
#pragma unroll
        for (int r = 0; r < 16; r++) oT[dt][r] *= scale;
      m_run = mn;
    }
    const float mnl = (m_run == NINF) ? 3.0e38f : m_run * L2E;
    float rs = 0.f;
#pragma unroll
    for (int r = 0; r < 16; r++) {
      p0[r] = exp2f(p0[r] * L2E - mnl);
      p1[r] = exp2f(p1[r] * L2E - mnl);
      rs += p0[r] + p1[r];
    }
    rs += __shfl_xor(rs, 32);
    l_run += rs;

#pragma unroll
    for (int kc = 0; kc < 4; kc++) {
      const float* P = (kc < 2) ? p0 : p1;
      const int rb = (kc & 1) * 8;
      uint32_t xa0 = packbf(P[rb + 0], P[rb + 1]);
      uint32_t xa1 = packbf(P[rb + 2], P[rb + 3]);
      uint32_t xb0 = packbf(P[rb + 4], P[rb + 5]);
      uint32_t xb1 = packbf(P[rb + 6], P[rb + 7]);
      uint32_t sa0 = (uint32_t)__shfl_xor((int)xa0, 32);
      uint32_t sa1 = (uint32_t)__shfl_xor((int)xa1, 32);
      uint32_t sb0 = (uint32_t)__shfl_xor((int)xb0, 32);
      uint32_t sb1 = (uint32_t)__shfl_xor((int)xb1, 32);
      union { uint32_t u[4]; bf16x8 v; } pf;
      pf.u[0] = hi ? sb0 : xa0;
      pf.u[1] = hi ? sb1 : xa1;
      pf.u[2] = hi ? xb0 : sa0;
      pf.u[3] = hi ? xb1 : sa1;
      __builtin_amdgcn_s_setprio(1);
#pragma unroll
      for (int dt = 0; dt < 2; dt++) {
        const int vr = dt * 32 + l31;
        const int c2 = kc * 2 + hi;
        bf16x8 vf = *(const bf16x8*)(Vc + vr * 64 + ((c2 ^ (vr & 7)) * 8));
        oT[dt] = __builtin_amdgcn_mfma_f32_32x32x16_bf16(vf, pf.v, oT[dt], 0, 0, 0);
      }
      __builtin_amdgcn_s_setprio(0);
    }

    __syncthreads();
  }

  const float rl = needs_merge ? 1.0f : ((l_run > 0.f) ? 1.0f / l_run : 0.f);
  bf16_t* Ot = (bf16_t*)Ks + wv * 2048;
#pragma unroll
  for (int dt = 0; dt < 2; dt++)
#pragma unroll
    for (int r = 0; r < 16; r++) {
      int chunkq = dt * 4 + (r >> 2);
      int el = (r & 3) + 4 * hi;
      Ot[l31 * 64 + ((chunkq ^ (l31 & 7)) * 8) + el] = (__bf16)(oT[dt][r] * rl);
    }
  __syncthreads();
  if (needs_merge) {
    bf16_t* dst = ((chunk < 3) ? (Op0 + (size_t)chunk * CHELEMS) : Op3)
                + ((size_t)(bh * 16 + qblk) * 128) * 64;
#pragma unroll
    for (int it = 0; it < 4; it++) {
      int qr2 = (lane >> 3) + it * 8;
      int cc = lane & 7;
      bf16x8 vv = *(const bf16x8*)(Ot + qr2 * 64 + ((cc ^ (qr2 & 7)) * 8));
      *(bf16x8*)(&dst[(size_t)(wv * 32 + qr2) * 64 + cc * 8]) = vv;
    }
    if (hi == 0) {
      size_t sidx = ((size_t)(chunk * 32 + bh) * 16 + qblk) * 128 + wv * 32 + l31;
      Mst[sidx] = m_run;
      Lst[sidx] = l_run;
    }
  } else {
#pragma unroll
    for (int it = 0; it < 4; it++) {
      int qr2 = (lane >> 3) + it * 8;
      int cc = lane & 7;
      bf16x8 vv = *(const bf16x8*)(Ot + qr2 * 64 + ((cc ^ (qr2 & 7)) * 8));
      *(bf16x8*)(&O[(size_t)(b * S_ + q0 + wv * 32 + qr2) * D_ + h * 64 + cc * 8]) = vv;
    }
  }
}

// ---------------- split-KV merge over nch = ceil(nt/8) chunks ----------------
__global__ __launch_bounds__(256) void attn_merge_kernel(const bf16_t* __restrict__ Op0,
                                                         const bf16_t* __restrict__ Op3,
                                                         const float* __restrict__ Mst,
                                                         const float* __restrict__ Lst,
                                                         const int* __restrict__ pos,
                                                         bf16_t* __restrict__ O) {
  __shared__ int wmax_s[4];
  const int t = threadIdx.x;
  const int bid = blockIdx.x;
  const int bh = (bid & 7) * 4 + ((bid >> 3) & 3);
  const int qblk = 15 - (bid >> 5);
  const int b = bh >> 4, h = bh & 15;
  const int q0 = qblk * 128;

  int p = pos[b * S_ + q0 + (t & 127)];
#pragma unroll
  for (int off = 1; off < 64; off <<= 1) p = max(p, __shfl_xor(p, off));
  if ((t & 63) == 0) wmax_s[t >> 6] = p;
  __syncthreads();
  int mp = max(max(wmax_s[0], wmax_s[1]), max(wmax_s[2], wmax_s[3]));
  const int nt = min(S_ / KVBLK, (mp >> 6) + 1);
  const int nch = (nt + CHTILES - 1) / CHTILES;
  if (nch <= 1) return;

  const int r = t >> 1, dh = (t & 1) * 32;
  const size_t rowoff = ((size_t)(bh * 16 + qblk) * 128 + r) * 64 + dh;

  float mc[4], lc[4];
  float m = -1e30f;
  for (int c = 0; c < nch; c++) {
    size_t sidx = ((size_t)(c * 32 + bh) * 16 + qblk) * 128 + r;
    mc[c] = Mst[sidx];
    lc[c] = Lst[sidx];
    m = fmaxf(m, mc[c]);
  }
  float accv[32];
#pragma unroll
  for (int j = 0; j < 32; j++) accv[j] = 0.f;
  float lt = 0.f;
  for (int c = 0; c < nch; c++) {
    float wgt = exp2f((mc[c] - m) * L2E);
    lt += lc[c] * wgt;
    const bf16_t* pc = ((c < 3) ? (Op0 + (size_t)c * CHELEMS) : Op3) + rowoff;
#pragma unroll
    for (int cc4 = 0; cc4 < 4; cc4++) {
      bf16x8 v = *(const bf16x8*)(pc + cc4 * 8);
#pragma unroll
      for (int j = 0; j < 8; j++) accv[cc4 * 8 + j] += wgt * (float)v[j];
    }
  }
  const float rl = (lt > 0.f) ? 1.0f / lt : 0.f;
  bf16_t* dst = O + (size_t)(b * S_ + q0 + r) * D_ + h * 64 + dh;
#pragma unroll
  for (int cc4 = 0; cc4 < 4; cc4++) {
    bf16x8 o;
#pragma unroll
    for (int j = 0; j < 8; j++) o[j] = (__bf16)(accv[cc4 * 8 + j] * rl);
    *(bf16x8*)(dst + cc4 * 8) = o;
  }
}

extern "C" void kernel_launch(void* const* d_in, const int* in_sizes, int n_in,
                              void* d_out, int out_size, void* d_ws, size_t ws_size,
                              hipStream_t stream) {
  const float* inputs = (const float*)d_in[0];
  const int* positions = (const int*)d_in[1];
  const float* W_in = (const float*)d_in[2];
  const float* W_out = (const float*)d_in[3];
  float* out = (float*)d_out;

  bf16_t* X_bf = (bf16_t*)d_ws;                       // 4096*1024 (dead after qkv-gemm)
  bf16_t* Win_bf = X_bf + (size_t)4096 * 1024;        // 3072*1024 (dead after qkv-gemm)
  bf16_t* Wout_bf = Win_bf + (size_t)3072 * 1024;     // live until gemm2
  bf16_t* scratch = Wout_bf + (size_t)1024 * 1024;    // 4096*3072 (dead: qkv never stored)
  bf16_t* Qb = scratch + (size_t)4096 * 3072;
  bf16_t* Kb = Qb + (size_t)B_ * H_ * S_ * HD_;
  bf16_t* Vtb = Kb + (size_t)B_ * H_ * S_ * HD_;
  bf16_t* Ob = Vtb + (size_t)B_ * H_ * S_ * HD_;

  bf16_t* Op0 = scratch;
  bf16_t* Op3 = X_bf;
  float* Mst = (float*)Win_bf;
  float* Lst = Mst + (size_t)4 * 32 * 16 * 128;

  cast3_bf16_kernel<<<dim3(2048), dim3(256), 0, stream>>>(
      inputs, X_bf, (4096 * 1024) / 4,
      W_in, Win_bf, (3072 * 1024) / 4,
      W_out, Wout_bf, (1024 * 1024) / 4);

  gemm_qkv_rope<<<dim3(192), dim3(512), 0, stream>>>(X_bf, Win_bf, positions, Qb, Kb, Vtb);

  attn_kernel<<<dim3(2048), dim3(256), 0, stream>>>(Qb, Kb, Vtb, positions, Ob, Op0, Op3, Mst, Lst);
  attn_merge_kernel<<<dim3(512), dim3(256), 0, stream>>>(Op0, Op3, Mst, Lst, positions, Ob);

  gemm_bt64<float><<<dim3(512), dim3(256), 0, stream>>>(Ob, Wout_bf, out, 4096, 1024, 1024);
}